// Round 2
// baseline (1735.236 us; speedup 1.0000x reference)
//
#include <hip/hip_runtime.h>
#include <hip/hip_bf16.h>

// GAT GNN: N=50000 nodes, E=800000 edges (+N self loops), C=64, H=4, L=3, NG=256
// Pipeline: input GEMM+relu -> 3x [xh GEMM + attn logits, per-node softmax-agg
// + LN + relu + residual] -> mean pool -> output GEMM.
// R1: k_xh __launch_bounds__(256,1) to stop wreg[64] spill + 4-node ILP;
//     xh stored bf16 to halve k_agg gather bytes (als/ald stay fp32).

__device__ __forceinline__ float wave_sum(float v) {
#pragma unroll
  for (int d = 32; d > 0; d >>= 1) v += __shfl_xor(v, d, 64);
  return v;
}

__device__ __forceinline__ float lrelu02(float v) { return v > 0.f ? v : 0.2f * v; }

__device__ __forceinline__ unsigned short f2bf(float f) {
  unsigned u = __float_as_uint(f);
  return (unsigned short)((u + 0x7fffu + ((u >> 16) & 1u)) >> 16);
}
__device__ __forceinline__ float bf2f(unsigned short s) {
  return __uint_as_float(((unsigned)s) << 16);
}

// h = relu(x @ W_in + b_in); x [N,32], W_in [32,64] -> h [N,64]. One wave/node.
__global__ __launch_bounds__(256) void k_input(const float* __restrict__ x,
    const float* __restrict__ Win, const float* __restrict__ bin,
    float* __restrict__ h, int N)
{
  int n = (blockIdx.x * 256 + threadIdx.x) >> 6;
  int lane = threadIdx.x & 63;
  if (n >= N) return;
  float xv = (lane < 32) ? x[n * 32 + lane] : 0.f;
  float acc = bin[lane];
#pragma unroll
  for (int k = 0; k < 32; ++k)
    acc = fmaf(__shfl(xv, k, 64), Win[k * 64 + lane], acc);
  h[n * 64 + lane] = fmaxf(acc, 0.f);
}

__global__ void k_set1(int* __restrict__ p, int n) {
  int t = blockIdx.x * blockDim.x + threadIdx.x;
  if (t < n) p[t] = 1;
}

__global__ void k_count(const int* __restrict__ dst, int* __restrict__ cnt, int E) {
  int t = blockIdx.x * blockDim.x + threadIdx.x;
  if (t < E) atomicAdd(&cnt[dst[t]], 1);
}

// Single-block exclusive scan of counter[0..N) -> rowstart[0..N]; also writes
// exclusive value back into counter[] (used as running fill cursor).
__global__ __launch_bounds__(1024) void k_scan(int* __restrict__ counter,
                                               int* __restrict__ rowstart, int N)
{
  __shared__ int wsums[16];
  __shared__ int s_carry;
  int tid = threadIdx.x, lane = tid & 63, wid = tid >> 6;
  if (tid == 0) s_carry = 0;
  __syncthreads();
  for (int base = 0; base < N; base += 1024) {
    int i = base + tid;
    int v = (i < N) ? counter[i] : 0;
    int x = v;
#pragma unroll
    for (int d = 1; d < 64; d <<= 1) {
      int y = __shfl_up(x, d, 64);
      if (lane >= d) x += y;
    }
    if (lane == 63) wsums[wid] = x;
    __syncthreads();
    if (wid == 0) {
      int s = (lane < 16) ? wsums[lane] : 0;
#pragma unroll
      for (int d = 1; d < 16; d <<= 1) {
        int y = __shfl_up(s, d, 64);
        if (lane >= d) s += y;
      }
      if (lane < 16) wsums[lane] = s;
    }
    __syncthreads();
    int carry = s_carry;
    int woff = (wid > 0) ? wsums[wid - 1] : 0;
    int excl = carry + woff + (x - v);
    if (i < N) { rowstart[i] = excl; counter[i] = excl; }
    int total = wsums[15];
    __syncthreads();
    if (tid == 0) s_carry = carry + total;
    __syncthreads();
  }
  if (threadIdx.x == 0) rowstart[N] = s_carry;
}

// Scatter edges (incl. self loops) into dst-grouped order: srcs[pos] = src.
__global__ void k_fill(const int* __restrict__ src, const int* __restrict__ dst,
                       int* __restrict__ counter, int* __restrict__ srcs, int E, int N)
{
  int t = blockIdx.x * blockDim.x + threadIdx.x;
  if (t >= E + N) return;
  int s, d;
  if (t < E) { s = src[t]; d = dst[t]; } else { s = t - E; d = s; }
  int pos = atomicAdd(&counter[d], 1);
  srcs[pos] = s;
}

// xh[n,256] = h[n,:] @ Wg[64,256] (stored bf16); al_s/al_d[n,h] from fp32 accs.
// Thread tid owns output column tid; W column cached in 64 VGPRs (launch_bounds
// (256,1) -> VGPR cap 512, no spill); 4 nodes in flight for FMA-latency ILP.
__global__ __launch_bounds__(256, 1) void k_xh(const float* __restrict__ h,
    const float* __restrict__ Wg, const float* __restrict__ asrc,
    const float* __restrict__ adst, unsigned short* __restrict__ xhb,
    float* __restrict__ als, float* __restrict__ ald, int N)
{
  int tid = threadIdx.x;
  int lane = tid & 63, wid = tid >> 6;
  float wreg[64];
#pragma unroll
  for (int k = 0; k < 64; ++k) wreg[k] = Wg[k * 256 + tid];
  float avs = asrc[tid], avd = adst[tid];
  int n0 = blockIdx.x * 64;
  int nend = n0 + 64 < N ? n0 + 64 : N;
  int n = n0;
  for (; n + 3 < nend; n += 4) {
    const float* hp = h + (size_t)n * 64 + lane;
    float hv0 = hp[0], hv1 = hp[64], hv2 = hp[128], hv3 = hp[192];
    float a0 = 0.f, a1 = 0.f, a2 = 0.f, a3 = 0.f;
#pragma unroll
    for (int k = 0; k < 64; ++k) {
      float w = wreg[k];
      a0 = fmaf(__shfl(hv0, k, 64), w, a0);
      a1 = fmaf(__shfl(hv1, k, 64), w, a1);
      a2 = fmaf(__shfl(hv2, k, 64), w, a2);
      a3 = fmaf(__shfl(hv3, k, 64), w, a3);
    }
    xhb[(size_t)(n + 0) * 256 + tid] = f2bf(a0);
    xhb[(size_t)(n + 1) * 256 + tid] = f2bf(a1);
    xhb[(size_t)(n + 2) * 256 + tid] = f2bf(a2);
    xhb[(size_t)(n + 3) * 256 + tid] = f2bf(a3);
    float s0 = wave_sum(a0 * avs), d0 = wave_sum(a0 * avd);
    float s1 = wave_sum(a1 * avs), d1 = wave_sum(a1 * avd);
    float s2 = wave_sum(a2 * avs), d2 = wave_sum(a2 * avd);
    float s3 = wave_sum(a3 * avs), d3 = wave_sum(a3 * avd);
    if (lane == 0) {
      als[(n + 0) * 4 + wid] = s0; ald[(n + 0) * 4 + wid] = d0;
      als[(n + 1) * 4 + wid] = s1; ald[(n + 1) * 4 + wid] = d1;
      als[(n + 2) * 4 + wid] = s2; ald[(n + 2) * 4 + wid] = d2;
      als[(n + 3) * 4 + wid] = s3; ald[(n + 3) * 4 + wid] = d3;
    }
  }
  for (; n < nend; ++n) {
    float hv = h[(size_t)n * 64 + lane];
    float acc = 0.f;
#pragma unroll
    for (int k = 0; k < 64; ++k)
      acc = fmaf(__shfl(hv, k, 64), wreg[k], acc);
    xhb[(size_t)n * 256 + tid] = f2bf(acc);
    float ps = wave_sum(acc * avs);
    float pd = wave_sum(acc * avd);
    if (lane == 0) { als[n * 4 + wid] = ps; ald[n * 4 + wid] = pd; }
  }
}

// One wave per node: two-pass softmax over incoming edges + weighted aggregate
// of bf16 xh[src], head-mean, bias, LayerNorm, relu, residual (in-place on h).
__global__ __launch_bounds__(256) void k_agg(const unsigned short* __restrict__ xhb,
    const float* __restrict__ als, const float* __restrict__ ald,
    const int* __restrict__ rowstart, const int* __restrict__ srcs,
    const float* __restrict__ bias, const float* __restrict__ g,
    const float* __restrict__ b, float* __restrict__ h, int N, int doRes)
{
  int n = (blockIdx.x * 256 + threadIdx.x) >> 6;
  int lane = threadIdx.x & 63;
  if (n >= N) return;
  int beg = rowstart[n], end = rowstart[n + 1];
  float ad0 = ald[n * 4 + 0], ad1 = ald[n * 4 + 1];
  float ad2 = ald[n * 4 + 2], ad3 = ald[n * 4 + 3];
  float m0 = -1e30f, m1 = -1e30f, m2 = -1e30f, m3 = -1e30f;
  for (int i = beg; i < end; ++i) {
    int s = srcs[i];
    m0 = fmaxf(m0, lrelu02(als[s * 4 + 0] + ad0));
    m1 = fmaxf(m1, lrelu02(als[s * 4 + 1] + ad1));
    m2 = fmaxf(m2, lrelu02(als[s * 4 + 2] + ad2));
    m3 = fmaxf(m3, lrelu02(als[s * 4 + 3] + ad3));
  }
  float l0 = 0, l1 = 0, l2 = 0, l3 = 0;
  float a0 = 0, a1 = 0, a2 = 0, a3 = 0;
  for (int i = beg; i < end; ++i) {
    int s = srcs[i];
    float p0 = __expf(lrelu02(als[s * 4 + 0] + ad0) - m0);
    float p1 = __expf(lrelu02(als[s * 4 + 1] + ad1) - m1);
    float p2 = __expf(lrelu02(als[s * 4 + 2] + ad2) - m2);
    float p3 = __expf(lrelu02(als[s * 4 + 3] + ad3) - m3);
    l0 += p0; l1 += p1; l2 += p2; l3 += p3;
    const unsigned short* xs = xhb + (size_t)s * 256;
    a0 = fmaf(p0, bf2f(xs[lane]), a0);
    a1 = fmaf(p1, bf2f(xs[64 + lane]), a1);
    a2 = fmaf(p2, bf2f(xs[128 + lane]), a2);
    a3 = fmaf(p3, bf2f(xs[192 + lane]), a3);
  }
  float o = 0.25f * (a0 / (l0 + 1e-16f) + a1 / (l1 + 1e-16f) +
                     a2 / (l2 + 1e-16f) + a3 / (l3 + 1e-16f)) + bias[lane];
  float mu = wave_sum(o) * 0.015625f;
  float dv = o - mu;
  float var = wave_sum(dv * dv) * 0.015625f;
  float y = dv * rsqrtf(var + 1e-5f) * g[lane] + b[lane];
  float r = fmaxf(y, 0.f);
  if (doRes) r += h[n * 64 + lane];
  h[n * 64 + lane] = r;
}

__global__ void k_zero(float* __restrict__ p, int n) {
  int t = blockIdx.x * blockDim.x + threadIdx.x;
  if (t < n) p[t] = 0.f;
}

__global__ void k_pool(const float* __restrict__ h, const int* __restrict__ batch,
                       float* __restrict__ pool, float* __restrict__ cnt, int N)
{
  int t = blockIdx.x * blockDim.x + threadIdx.x;
  if (t >= N * 64) return;
  int n = t >> 6, c = t & 63;
  int gid = batch[n];
  atomicAdd(&pool[gid * 64 + c], h[t]);
  if (c == 0) atomicAdd(&cnt[gid], 1.f);
}

__global__ void k_out(const float* __restrict__ pool, const float* __restrict__ cnt,
                      const float* __restrict__ Wout, const float* __restrict__ bout,
                      float* __restrict__ out, int NG)
{
  int t = blockIdx.x * blockDim.x + threadIdx.x;
  if (t >= NG * 32) return;
  int gid = t >> 5, j = t & 31;
  float s = 0.f;
#pragma unroll
  for (int c = 0; c < 64; ++c) s = fmaf(pool[gid * 64 + c], Wout[c * 32 + j], s);
  out[t] = s / fmaxf(cnt[gid], 1.f) + bout[j];
}

extern "C" void kernel_launch(void* const* d_in, const int* in_sizes, int n_in,
                              void* d_out, int out_size, void* d_ws, size_t ws_size,
                              hipStream_t stream) {
  const float* x    = (const float*)d_in[0];
  const int*   ei   = (const int*)d_in[1];
  const int*   batch= (const int*)d_in[2];
  const float* Win  = (const float*)d_in[3];
  const float* bin  = (const float*)d_in[4];
  const float* Wgat = (const float*)d_in[5];
  const float* asrc = (const float*)d_in[6];
  const float* adst = (const float*)d_in[7];
  const float* bgat = (const float*)d_in[8];
  const float* lng  = (const float*)d_in[9];
  const float* lnb  = (const float*)d_in[10];
  const float* Wout = (const float*)d_in[11];
  const float* bout = (const float*)d_in[12];
  float* out = (float*)d_out;

  int N  = in_sizes[0] / 32;
  int E  = in_sizes[1] / 2;
  int NG = out_size / 32;
  int L  = in_sizes[5] / (64 * 256);

  char* w = (char*)d_ws;
  unsigned short* xhb = (unsigned short*)w; w += (size_t)N * 256 * 2;
  float* h  = (float*)w;       w += (size_t)N * 64 * 4;
  float* als= (float*)w;       w += (size_t)N * 4 * 4;
  float* ald= (float*)w;       w += (size_t)N * 4 * 4;
  int* rowstart = (int*)w;     w += (size_t)(N + 1) * 4;
  int* counter  = (int*)w;     w += (size_t)N * 4;
  int* srcs     = (int*)w;     w += (size_t)(E + N) * 4;
  float* pool   = (float*)w;   w += (size_t)NG * 64 * 4;
  float* cnt    = (float*)w;   w += (size_t)NG * 4;

  const int* esrc = ei;       // edge_index[0]
  const int* edst = ei + E;   // edge_index[1]

  // input layer
  k_input<<<(N + 3) / 4, 256, 0, stream>>>(x, Win, bin, h, N);

  // CSR build (dst-grouped), self-loops included via deg init = 1
  k_set1<<<(N + 255) / 256, 256, 0, stream>>>(counter, N);
  k_count<<<(E + 255) / 256, 256, 0, stream>>>(edst, counter, E);
  k_scan<<<1, 1024, 0, stream>>>(counter, rowstart, N);
  k_fill<<<(E + N + 255) / 256, 256, 0, stream>>>(esrc, edst, counter, srcs, E, N);

  for (int i = 0; i < L; ++i) {
    k_xh<<<(N + 63) / 64, 256, 0, stream>>>(h, Wgat + (size_t)i * 64 * 256,
        asrc + i * 256, adst + i * 256, xhb, als, ald, N);
    k_agg<<<(N + 3) / 4, 256, 0, stream>>>(xhb, als, ald, rowstart, srcs,
        bgat + i * 64, lng + i * 64, lnb + i * 64, h, N, i > 0 ? 1 : 0);
  }

  // mean pool + output GEMM
  k_zero<<<(NG * 65 + 255) / 256, 256, 0, stream>>>(pool, NG * 65); // pool then cnt (contiguous)
  k_pool<<<(N * 64 + 255) / 256, 256, 0, stream>>>(h, batch, pool, cnt, N);
  k_out<<<(NG * 32 + 255) / 256, 256, 0, stream>>>(pool, cnt, Wout, bout, out, NG);
}

// Round 3
// 1127.004 us; speedup vs baseline: 1.5397x; 1.5397x over previous
//
#include <hip/hip_runtime.h>
#include <hip/hip_bf16.h>

// GAT GNN: N=50000 nodes, E=800000 edges (+N self loops), C=64, H=4, L=3, NG=256
// R2: k_xh/k_input GEMMs use wave-uniform scalar loads of h-row (s_load) +
//     per-thread W column in VGPRs -> pure v_fma inner loop, no __shfl/DS ops.
//     xh stays bf16 (halves k_agg gather bytes); als/ald fp32.

__device__ __forceinline__ float wave_sum(float v) {
#pragma unroll
  for (int d = 32; d > 0; d >>= 1) v += __shfl_xor(v, d, 64);
  return v;
}

__device__ __forceinline__ float lrelu02(float v) { return v > 0.f ? v : 0.2f * v; }

__device__ __forceinline__ unsigned short f2bf(float f) {
  unsigned u = __float_as_uint(f);
  return (unsigned short)((u + 0x7fffu + ((u >> 16) & 1u)) >> 16);
}
__device__ __forceinline__ float bf2f(unsigned short s) {
  return __uint_as_float(((unsigned)s) << 16);
}

// h = relu(x @ W_in + b_in); x [N,32], W_in [32,64] -> h [N,64].
// Block = 64 nodes; thread owns column col for 16 nodes; x-row via s_load.
__global__ __launch_bounds__(256, 4) void k_input(const float* __restrict__ x,
    const float* __restrict__ Win, const float* __restrict__ bin,
    float* __restrict__ h, int N)
{
  int col = threadIdx.x & 63;
  int sub = threadIdx.x >> 6;
  float wreg[32];
#pragma unroll
  for (int k = 0; k < 32; ++k) wreg[k] = Win[k * 64 + col];
  float bv = bin[col];
  int n0 = blockIdx.x * 64 + sub * 16;
  int nend = n0 + 16 < N ? n0 + 16 : N;
  for (int n = n0; n < nend; ++n) {
    const float* xp = x + (size_t)n * 32;
    float c0 = 0.f, c1 = 0.f, c2 = 0.f, c3 = 0.f;
#pragma unroll
    for (int k = 0; k < 32; k += 4) {
      c0 = fmaf(xp[k + 0], wreg[k + 0], c0);
      c1 = fmaf(xp[k + 1], wreg[k + 1], c1);
      c2 = fmaf(xp[k + 2], wreg[k + 2], c2);
      c3 = fmaf(xp[k + 3], wreg[k + 3], c3);
    }
    h[(size_t)n * 64 + col] = fmaxf((c0 + c1) + (c2 + c3) + bv, 0.f);
  }
}

__global__ void k_set1(int* __restrict__ p, int n) {
  int t = blockIdx.x * blockDim.x + threadIdx.x;
  if (t < n) p[t] = 1;
}

__global__ void k_count(const int* __restrict__ dst, int* __restrict__ cnt, int E) {
  int t = blockIdx.x * blockDim.x + threadIdx.x;
  if (t < E) atomicAdd(&cnt[dst[t]], 1);
}

// Single-block exclusive scan of counter[0..N) -> rowstart[0..N]; also writes
// exclusive value back into counter[] (used as running fill cursor).
__global__ __launch_bounds__(1024) void k_scan(int* __restrict__ counter,
                                               int* __restrict__ rowstart, int N)
{
  __shared__ int wsums[16];
  __shared__ int s_carry;
  int tid = threadIdx.x, lane = tid & 63, wid = tid >> 6;
  if (tid == 0) s_carry = 0;
  __syncthreads();
  for (int base = 0; base < N; base += 1024) {
    int i = base + tid;
    int v = (i < N) ? counter[i] : 0;
    int x = v;
#pragma unroll
    for (int d = 1; d < 64; d <<= 1) {
      int y = __shfl_up(x, d, 64);
      if (lane >= d) x += y;
    }
    if (lane == 63) wsums[wid] = x;
    __syncthreads();
    if (wid == 0) {
      int s = (lane < 16) ? wsums[lane] : 0;
#pragma unroll
      for (int d = 1; d < 16; d <<= 1) {
        int y = __shfl_up(s, d, 64);
        if (lane >= d) s += y;
      }
      if (lane < 16) wsums[lane] = s;
    }
    __syncthreads();
    int carry = s_carry;
    int woff = (wid > 0) ? wsums[wid - 1] : 0;
    int excl = carry + woff + (x - v);
    if (i < N) { rowstart[i] = excl; counter[i] = excl; }
    int total = wsums[15];
    __syncthreads();
    if (tid == 0) s_carry = carry + total;
    __syncthreads();
  }
  if (threadIdx.x == 0) rowstart[N] = s_carry;
}

// Scatter edges (incl. self loops) into dst-grouped order: srcs[pos] = src.
__global__ void k_fill(const int* __restrict__ src, const int* __restrict__ dst,
                       int* __restrict__ counter, int* __restrict__ srcs, int E, int N)
{
  int t = blockIdx.x * blockDim.x + threadIdx.x;
  if (t >= E + N) return;
  int s, d;
  if (t < E) { s = src[t]; d = dst[t]; } else { s = t - E; d = s; }
  int pos = atomicAdd(&counter[d], 1);
  srcs[pos] = s;
}

// xh[n,256] = h[n,:] @ Wg[64,256] (stored bf16); al_s/al_d from fp32 accs.
// Thread tid owns column tid; W column in 64 VGPRs; h-row values are
// wave-uniform -> scalar loads (s_load), inner loop = pure v_fma_f32.
// 2 nodes x 2 chains for FMA-latency ILP.
__global__ __launch_bounds__(256, 4) void k_xh(const float* __restrict__ h,
    const float* __restrict__ Wg, const float* __restrict__ asrc,
    const float* __restrict__ adst, unsigned short* __restrict__ xhb,
    float* __restrict__ als, float* __restrict__ ald, int N)
{
  int tid = threadIdx.x;
  int lane = tid & 63, wid = tid >> 6;
  float wreg[64];
#pragma unroll
  for (int k = 0; k < 64; ++k) wreg[k] = Wg[k * 256 + tid];
  float avs = asrc[tid], avd = adst[tid];
  int n0 = blockIdx.x * 64;
  int nend = n0 + 64 < N ? n0 + 64 : N;
  int n = n0;
  for (; n + 1 < nend; n += 2) {
    const float* hp0 = h + (size_t)n * 64;
    const float* hp1 = hp0 + 64;
    float a0 = 0.f, b0 = 0.f, a1 = 0.f, b1 = 0.f;
#pragma unroll
    for (int k = 0; k < 64; k += 2) {
      a0 = fmaf(hp0[k + 0], wreg[k + 0], a0);
      b0 = fmaf(hp0[k + 1], wreg[k + 1], b0);
      a1 = fmaf(hp1[k + 0], wreg[k + 0], a1);
      b1 = fmaf(hp1[k + 1], wreg[k + 1], b1);
    }
    float x0 = a0 + b0, x1 = a1 + b1;
    xhb[(size_t)(n + 0) * 256 + tid] = f2bf(x0);
    xhb[(size_t)(n + 1) * 256 + tid] = f2bf(x1);
    float s0 = wave_sum(x0 * avs), d0 = wave_sum(x0 * avd);
    float s1 = wave_sum(x1 * avs), d1 = wave_sum(x1 * avd);
    if (lane == 0) {
      als[(n + 0) * 4 + wid] = s0; ald[(n + 0) * 4 + wid] = d0;
      als[(n + 1) * 4 + wid] = s1; ald[(n + 1) * 4 + wid] = d1;
    }
  }
  for (; n < nend; ++n) {
    const float* hp = h + (size_t)n * 64;
    float c0 = 0.f, c1 = 0.f;
#pragma unroll
    for (int k = 0; k < 64; k += 2) {
      c0 = fmaf(hp[k + 0], wreg[k + 0], c0);
      c1 = fmaf(hp[k + 1], wreg[k + 1], c1);
    }
    float acc = c0 + c1;
    xhb[(size_t)n * 256 + tid] = f2bf(acc);
    float ps = wave_sum(acc * avs);
    float pd = wave_sum(acc * avd);
    if (lane == 0) { als[n * 4 + wid] = ps; ald[n * 4 + wid] = pd; }
  }
}

// One wave per node: two-pass softmax over incoming edges + weighted aggregate
// of bf16 xh[src], head-mean, bias, LayerNorm, relu, residual (in-place on h).
__global__ __launch_bounds__(256) void k_agg(const unsigned short* __restrict__ xhb,
    const float* __restrict__ als, const float* __restrict__ ald,
    const int* __restrict__ rowstart, const int* __restrict__ srcs,
    const float* __restrict__ bias, const float* __restrict__ g,
    const float* __restrict__ b, float* __restrict__ h, int N, int doRes)
{
  int n = (blockIdx.x * 256 + threadIdx.x) >> 6;
  int lane = threadIdx.x & 63;
  if (n >= N) return;
  int beg = rowstart[n], end = rowstart[n + 1];
  float ad0 = ald[n * 4 + 0], ad1 = ald[n * 4 + 1];
  float ad2 = ald[n * 4 + 2], ad3 = ald[n * 4 + 3];
  float m0 = -1e30f, m1 = -1e30f, m2 = -1e30f, m3 = -1e30f;
  for (int i = beg; i < end; ++i) {
    int s = srcs[i];
    m0 = fmaxf(m0, lrelu02(als[s * 4 + 0] + ad0));
    m1 = fmaxf(m1, lrelu02(als[s * 4 + 1] + ad1));
    m2 = fmaxf(m2, lrelu02(als[s * 4 + 2] + ad2));
    m3 = fmaxf(m3, lrelu02(als[s * 4 + 3] + ad3));
  }
  float l0 = 0, l1 = 0, l2 = 0, l3 = 0;
  float a0 = 0, a1 = 0, a2 = 0, a3 = 0;
  for (int i = beg; i < end; ++i) {
    int s = srcs[i];
    float p0 = __expf(lrelu02(als[s * 4 + 0] + ad0) - m0);
    float p1 = __expf(lrelu02(als[s * 4 + 1] + ad1) - m1);
    float p2 = __expf(lrelu02(als[s * 4 + 2] + ad2) - m2);
    float p3 = __expf(lrelu02(als[s * 4 + 3] + ad3) - m3);
    l0 += p0; l1 += p1; l2 += p2; l3 += p3;
    const unsigned short* xs = xhb + (size_t)s * 256;
    a0 = fmaf(p0, bf2f(xs[lane]), a0);
    a1 = fmaf(p1, bf2f(xs[64 + lane]), a1);
    a2 = fmaf(p2, bf2f(xs[128 + lane]), a2);
    a3 = fmaf(p3, bf2f(xs[192 + lane]), a3);
  }
  float o = 0.25f * (a0 / (l0 + 1e-16f) + a1 / (l1 + 1e-16f) +
                     a2 / (l2 + 1e-16f) + a3 / (l3 + 1e-16f)) + bias[lane];
  float mu = wave_sum(o) * 0.015625f;
  float dv = o - mu;
  float var = wave_sum(dv * dv) * 0.015625f;
  float y = dv * rsqrtf(var + 1e-5f) * g[lane] + b[lane];
  float r = fmaxf(y, 0.f);
  if (doRes) r += h[n * 64 + lane];
  h[n * 64 + lane] = r;
}

__global__ void k_zero(float* __restrict__ p, int n) {
  int t = blockIdx.x * blockDim.x + threadIdx.x;
  if (t < n) p[t] = 0.f;
}

__global__ void k_pool(const float* __restrict__ h, const int* __restrict__ batch,
                       float* __restrict__ pool, float* __restrict__ cnt, int N)
{
  int t = blockIdx.x * blockDim.x + threadIdx.x;
  if (t >= N * 64) return;
  int n = t >> 6, c = t & 63;
  int gid = batch[n];
  atomicAdd(&pool[gid * 64 + c], h[t]);
  if (c == 0) atomicAdd(&cnt[gid], 1.f);
}

__global__ void k_out(const float* __restrict__ pool, const float* __restrict__ cnt,
                      const float* __restrict__ Wout, const float* __restrict__ bout,
                      float* __restrict__ out, int NG)
{
  int t = blockIdx.x * blockDim.x + threadIdx.x;
  if (t >= NG * 32) return;
  int gid = t >> 5, j = t & 31;
  float s = 0.f;
#pragma unroll
  for (int c = 0; c < 64; ++c) s = fmaf(pool[gid * 64 + c], Wout[c * 32 + j], s);
  out[t] = s / fmaxf(cnt[gid], 1.f) + bout[j];
}

extern "C" void kernel_launch(void* const* d_in, const int* in_sizes, int n_in,
                              void* d_out, int out_size, void* d_ws, size_t ws_size,
                              hipStream_t stream) {
  const float* x    = (const float*)d_in[0];
  const int*   ei   = (const int*)d_in[1];
  const int*   batch= (const int*)d_in[2];
  const float* Win  = (const float*)d_in[3];
  const float* bin  = (const float*)d_in[4];
  const float* Wgat = (const float*)d_in[5];
  const float* asrc = (const float*)d_in[6];
  const float* adst = (const float*)d_in[7];
  const float* bgat = (const float*)d_in[8];
  const float* lng  = (const float*)d_in[9];
  const float* lnb  = (const float*)d_in[10];
  const float* Wout = (const float*)d_in[11];
  const float* bout = (const float*)d_in[12];
  float* out = (float*)d_out;

  int N  = in_sizes[0] / 32;
  int E  = in_sizes[1] / 2;
  int NG = out_size / 32;
  int L  = in_sizes[5] / (64 * 256);

  char* w = (char*)d_ws;
  unsigned short* xhb = (unsigned short*)w; w += (size_t)N * 256 * 2;
  float* h  = (float*)w;       w += (size_t)N * 64 * 4;
  float* als= (float*)w;       w += (size_t)N * 4 * 4;
  float* ald= (float*)w;       w += (size_t)N * 4 * 4;
  int* rowstart = (int*)w;     w += (size_t)(N + 1) * 4;
  int* counter  = (int*)w;     w += (size_t)N * 4;
  int* srcs     = (int*)w;     w += (size_t)(E + N) * 4;
  float* pool   = (float*)w;   w += (size_t)NG * 64 * 4;
  float* cnt    = (float*)w;   w += (size_t)NG * 4;

  const int* esrc = ei;       // edge_index[0]
  const int* edst = ei + E;   // edge_index[1]

  // input layer
  k_input<<<(N + 63) / 64, 256, 0, stream>>>(x, Win, bin, h, N);

  // CSR build (dst-grouped), self-loops included via deg init = 1
  k_set1<<<(N + 255) / 256, 256, 0, stream>>>(counter, N);
  k_count<<<(E + 255) / 256, 256, 0, stream>>>(edst, counter, E);
  k_scan<<<1, 1024, 0, stream>>>(counter, rowstart, N);
  k_fill<<<(E + N + 255) / 256, 256, 0, stream>>>(esrc, edst, counter, srcs, E, N);

  for (int i = 0; i < L; ++i) {
    k_xh<<<(N + 63) / 64, 256, 0, stream>>>(h, Wgat + (size_t)i * 64 * 256,
        asrc + i * 256, adst + i * 256, xhb, als, ald, N);
    k_agg<<<(N + 3) / 4, 256, 0, stream>>>(xhb, als, ald, rowstart, srcs,
        bgat + i * 64, lng + i * 64, lnb + i * 64, h, N, i > 0 ? 1 : 0);
  }

  // mean pool + output GEMM
  k_zero<<<(NG * 65 + 255) / 256, 256, 0, stream>>>(pool, NG * 65); // pool then cnt (contiguous)
  k_pool<<<(N * 64 + 255) / 256, 256, 0, stream>>>(h, batch, pool, cnt, N);
  k_out<<<(NG * 32 + 255) / 256, 256, 0, stream>>>(pool, cnt, Wout, bout, out, NG);
}

// Round 4
// 721.395 us; speedup vs baseline: 2.4054x; 1.5623x over previous
//
#include <hip/hip_runtime.h>
#include <hip/hip_bf16.h>

// GAT GNN: N=50000 nodes, E=800000 edges (+N self loops), C=64, H=4, L=3, NG=256
// R3: k_agg edge-parallel softmax (lane-per-edge, p/s staged in per-wave LDS,
//     2-dword-per-lane gather = 2 ch x 2 heads); k_xh/k_input LDS-broadcast GEMM.

__device__ __forceinline__ float wave_sum(float v) {
#pragma unroll
  for (int d = 32; d > 0; d >>= 1) v += __shfl_xor(v, d, 64);
  return v;
}
__device__ __forceinline__ float wave_max(float v) {
#pragma unroll
  for (int d = 32; d > 0; d >>= 1) v = fmaxf(v, __shfl_xor(v, d, 64));
  return v;
}
__device__ __forceinline__ float lrelu02(float v) { return fmaxf(v, 0.2f * v); }

__device__ __forceinline__ unsigned short f2bf(float f) {
  unsigned u = __float_as_uint(f);
  return (unsigned short)((u + 0x7fffu + ((u >> 16) & 1u)) >> 16);
}

// h = relu(x @ W_in + b_in); x [N,32] staged in LDS, broadcast reads + FMA.
__global__ __launch_bounds__(256, 4) void k_input(const float* __restrict__ x,
    const float* __restrict__ Win, const float* __restrict__ bin,
    float* __restrict__ h, int N)
{
  __shared__ float xs[64 * 32];
  int tid = threadIdx.x;
  int lane = tid & 63, wid = tid >> 6;
  int n0 = blockIdx.x * 64;
  int nrows = N - n0; if (nrows > 64) nrows = 64;
  {
    const float4* srcp = (const float4*)(x + (size_t)n0 * 32);
    float4* dstp = (float4*)xs;
    for (int i = tid; i < nrows * 8; i += 256) dstp[i] = srcp[i];
  }
  float wreg[32];
#pragma unroll
  for (int k = 0; k < 32; ++k) wreg[k] = Win[k * 64 + lane];
  float bv = bin[lane];
  __syncthreads();
  int nbeg = wid * 16;
  int nlim = nbeg + 16; if (nlim > nrows) nlim = nrows;
  for (int nn = nbeg; nn < nlim; ++nn) {
    const float* r = xs + nn * 32;
    float c0 = 0.f, c1 = 0.f;
#pragma unroll
    for (int k = 0; k < 32; k += 2) {
      c0 = fmaf(r[k],     wreg[k],     c0);
      c1 = fmaf(r[k + 1], wreg[k + 1], c1);
    }
    h[(size_t)(n0 + nn) * 64 + lane] = fmaxf(c0 + c1 + bv, 0.f);
  }
}

__global__ void k_set1(int* __restrict__ p, int n) {
  int t = blockIdx.x * blockDim.x + threadIdx.x;
  if (t < n) p[t] = 1;
}

__global__ void k_count(const int* __restrict__ dst, int* __restrict__ cnt, int E) {
  int t = blockIdx.x * blockDim.x + threadIdx.x;
  if (t < E) atomicAdd(&cnt[dst[t]], 1);
}

// Single-block exclusive scan of counter[0..N) -> rowstart[0..N].
__global__ __launch_bounds__(1024) void k_scan(int* __restrict__ counter,
                                               int* __restrict__ rowstart, int N)
{
  __shared__ int wsums[16];
  __shared__ int s_carry;
  int tid = threadIdx.x, lane = tid & 63, wid = tid >> 6;
  if (tid == 0) s_carry = 0;
  __syncthreads();
  for (int base = 0; base < N; base += 1024) {
    int i = base + tid;
    int v = (i < N) ? counter[i] : 0;
    int x = v;
#pragma unroll
    for (int d = 1; d < 64; d <<= 1) {
      int y = __shfl_up(x, d, 64);
      if (lane >= d) x += y;
    }
    if (lane == 63) wsums[wid] = x;
    __syncthreads();
    if (wid == 0) {
      int s = (lane < 16) ? wsums[lane] : 0;
#pragma unroll
      for (int d = 1; d < 16; d <<= 1) {
        int y = __shfl_up(s, d, 64);
        if (lane >= d) s += y;
      }
      if (lane < 16) wsums[lane] = s;
    }
    __syncthreads();
    int carry = s_carry;
    int woff = (wid > 0) ? wsums[wid - 1] : 0;
    int excl = carry + woff + (x - v);
    if (i < N) { rowstart[i] = excl; counter[i] = excl; }
    int total = wsums[15];
    __syncthreads();
    if (tid == 0) s_carry = carry + total;
    __syncthreads();
  }
  if (threadIdx.x == 0) rowstart[N] = s_carry;
}

__global__ void k_fill(const int* __restrict__ src, const int* __restrict__ dst,
                       int* __restrict__ counter, int* __restrict__ srcs, int E, int N)
{
  int t = blockIdx.x * blockDim.x + threadIdx.x;
  if (t >= E + N) return;
  int s, d;
  if (t < E) { s = src[t]; d = dst[t]; } else { s = t - E; d = s; }
  int pos = atomicAdd(&counter[d], 1);
  srcs[pos] = s;
}

// xh[n,256] = h[n,:] @ Wg[64,256] (bf16 out); h-tile staged in LDS, broadcast
// ds_read + FMA; W column in 64 VGPRs; als/ald via wave reductions.
__global__ __launch_bounds__(256, 4) void k_xh(const float* __restrict__ h,
    const float* __restrict__ Wg, const float* __restrict__ asrc,
    const float* __restrict__ adst, unsigned short* __restrict__ xhb,
    float* __restrict__ als, float* __restrict__ ald, int N)
{
  __shared__ float hs[64 * 64];
  int tid = threadIdx.x;
  int lane = tid & 63, wid = tid >> 6;
  int n0 = blockIdx.x * 64;
  int nrows = N - n0; if (nrows > 64) nrows = 64;
  {
    const float4* srcp = (const float4*)(h + (size_t)n0 * 64);
    float4* dstp = (float4*)hs;
    for (int i = tid; i < nrows * 16; i += 256) dstp[i] = srcp[i];
  }
  float wreg[64];
#pragma unroll
  for (int k = 0; k < 64; ++k) wreg[k] = Wg[k * 256 + tid];
  float avs = asrc[tid], avd = adst[tid];
  __syncthreads();
  int nn = 0;
  for (; nn + 1 < nrows; nn += 2) {
    const float* r0 = hs + nn * 64;
    const float* r1 = r0 + 64;
    float a0 = 0.f, b0 = 0.f, a1 = 0.f, b1 = 0.f;
#pragma unroll
    for (int k = 0; k < 64; k += 2) {
      a0 = fmaf(r0[k],     wreg[k],     a0);
      b0 = fmaf(r0[k + 1], wreg[k + 1], b0);
      a1 = fmaf(r1[k],     wreg[k],     a1);
      b1 = fmaf(r1[k + 1], wreg[k + 1], b1);
    }
    float x0 = a0 + b0, x1 = a1 + b1;
    int n = n0 + nn;
    xhb[(size_t)n * 256 + tid] = f2bf(x0);
    xhb[(size_t)(n + 1) * 256 + tid] = f2bf(x1);
    float s0 = wave_sum(x0 * avs), d0 = wave_sum(x0 * avd);
    float s1 = wave_sum(x1 * avs), d1 = wave_sum(x1 * avd);
    if (lane == 0) {
      als[n * 4 + wid] = s0;       ald[n * 4 + wid] = d0;
      als[(n + 1) * 4 + wid] = s1; ald[(n + 1) * 4 + wid] = d1;
    }
  }
  if (nn < nrows) {
    const float* r0 = hs + nn * 64;
    float a0 = 0.f, b0 = 0.f;
#pragma unroll
    for (int k = 0; k < 64; k += 2) {
      a0 = fmaf(r0[k],     wreg[k],     a0);
      b0 = fmaf(r0[k + 1], wreg[k + 1], b0);
    }
    float x0 = a0 + b0;
    int n = n0 + nn;
    xhb[(size_t)n * 256 + tid] = f2bf(x0);
    float s0 = wave_sum(x0 * avs), d0 = wave_sum(x0 * avd);
    if (lane == 0) { als[n * 4 + wid] = s0; ald[n * 4 + wid] = d0; }
  }
}

// One wave per node. Edge-parallel softmax: lane e handles edge beg+e
// (coalesced srcs, 16B als gather, lrelu, wave-max, exp); p[4]+src staged in
// per-wave LDS. Serial gather loop: broadcast ds_read p/s + 2 dword loads/lane
// (lane owns 2 channels x 2 heads of the 512B bf16 row) + 4 FMA.
__global__ __launch_bounds__(256) void k_agg(const unsigned short* __restrict__ xhb,
    const float* __restrict__ als, const float* __restrict__ ald,
    const int* __restrict__ rowstart, const int* __restrict__ srcs,
    const float* __restrict__ bias, const float* __restrict__ g,
    const float* __restrict__ b, float* __restrict__ h, int N, int doRes)
{
  __shared__ float4 pb[4][64];
  __shared__ int sb[4][64];
  int lane = threadIdx.x & 63;
  int wid = threadIdx.x >> 6;
  int n = blockIdx.x * 4 + wid;
  if (n >= N) return;
  int beg = rowstart[n], end = rowstart[n + 1];
  int deg = end - beg;
  const float4 adv = *(const float4*)(ald + (size_t)n * 4);
  const unsigned* xu = (const unsigned*)xhb;
  bool lo32 = (lane < 32);

  float l0 = 0.f, l1 = 0.f, l2 = 0.f, l3 = 0.f;
  // acc: A = even channel, B = odd channel; 0 = head lane>>5, 1 = head 2+(lane>>5)
  float A0 = 0.f, B0 = 0.f, A1 = 0.f, B1 = 0.f;

  if (deg <= 64) {
    int e = beg + lane;
    int ce = (e < end) ? e : (end - 1);
    int s = srcs[ce];
    float4 av = *(const float4*)(als + (size_t)s * 4);
    float e0 = lrelu02(av.x + adv.x);
    float e1 = lrelu02(av.y + adv.y);
    float e2 = lrelu02(av.z + adv.z);
    float e3 = lrelu02(av.w + adv.w);
    bool act = (e < end);
    float m0 = wave_max(act ? e0 : -1e30f);
    float m1 = wave_max(act ? e1 : -1e30f);
    float m2 = wave_max(act ? e2 : -1e30f);
    float m3 = wave_max(act ? e3 : -1e30f);
    float p0 = act ? __expf(e0 - m0) : 0.f;
    float p1 = act ? __expf(e1 - m1) : 0.f;
    float p2 = act ? __expf(e2 - m2) : 0.f;
    float p3 = act ? __expf(e3 - m3) : 0.f;
    l0 = p0; l1 = p1; l2 = p2; l3 = p3;
    pb[wid][lane] = make_float4(p0, p1, p2, p3);
    sb[wid][lane] = s;
    for (int j = 0; j < deg; ++j) {
      float4 p = pb[wid][j];
      int sj = sb[wid][j];
      const unsigned* row = xu + (size_t)sj * 128;
      unsigned u0 = row[lane];
      unsigned u1 = row[64 + lane];
      float pA = lo32 ? p.x : p.y;
      float pB = lo32 ? p.z : p.w;
      A0 = fmaf(pA, __uint_as_float(u0 << 16), A0);
      B0 = fmaf(pA, __uint_as_float(u0 & 0xffff0000u), B0);
      A1 = fmaf(pB, __uint_as_float(u1 << 16), A1);
      B1 = fmaf(pB, __uint_as_float(u1 & 0xffff0000u), B1);
    }
  } else {
    float m0 = -1e30f, m1 = -1e30f, m2 = -1e30f, m3 = -1e30f;
    for (int base = beg; base < end; base += 64) {
      int e = base + lane;
      int ce = (e < end) ? e : (end - 1);
      int s = srcs[ce];
      float4 av = *(const float4*)(als + (size_t)s * 4);
      bool act = (e < end);
      m0 = fmaxf(m0, act ? lrelu02(av.x + adv.x) : -1e30f);
      m1 = fmaxf(m1, act ? lrelu02(av.y + adv.y) : -1e30f);
      m2 = fmaxf(m2, act ? lrelu02(av.z + adv.z) : -1e30f);
      m3 = fmaxf(m3, act ? lrelu02(av.w + adv.w) : -1e30f);
    }
    m0 = wave_max(m0); m1 = wave_max(m1); m2 = wave_max(m2); m3 = wave_max(m3);
    for (int base = beg; base < end; base += 64) {
      int e = base + lane;
      int ce = (e < end) ? e : (end - 1);
      int s = srcs[ce];
      float4 av = *(const float4*)(als + (size_t)s * 4);
      bool act = (e < end);
      float p0 = act ? __expf(lrelu02(av.x + adv.x) - m0) : 0.f;
      float p1 = act ? __expf(lrelu02(av.y + adv.y) - m1) : 0.f;
      float p2 = act ? __expf(lrelu02(av.z + adv.z) - m2) : 0.f;
      float p3 = act ? __expf(lrelu02(av.w + adv.w) - m3) : 0.f;
      l0 += p0; l1 += p1; l2 += p2; l3 += p3;
      pb[wid][lane] = make_float4(p0, p1, p2, p3);
      sb[wid][lane] = s;
      int cnt = end - base; if (cnt > 64) cnt = 64;
      for (int j = 0; j < cnt; ++j) {
        float4 p = pb[wid][j];
        int sj = sb[wid][j];
        const unsigned* row = xu + (size_t)sj * 128;
        unsigned u0 = row[lane];
        unsigned u1 = row[64 + lane];
        float pA = lo32 ? p.x : p.y;
        float pB = lo32 ? p.z : p.w;
        A0 = fmaf(pA, __uint_as_float(u0 << 16), A0);
        B0 = fmaf(pA, __uint_as_float(u0 & 0xffff0000u), B0);
        A1 = fmaf(pB, __uint_as_float(u1 << 16), A1);
        B1 = fmaf(pB, __uint_as_float(u1 & 0xffff0000u), B1);
      }
    }
  }

  l0 = wave_sum(l0); l1 = wave_sum(l1); l2 = wave_sum(l2); l3 = wave_sum(l3);
  float i0 = 1.f / (l0 + 1e-16f), i1 = 1.f / (l1 + 1e-16f);
  float i2 = 1.f / (l2 + 1e-16f), i3 = 1.f / (l3 + 1e-16f);
  float iA = lo32 ? i0 : i1;
  float iB = lo32 ? i2 : i3;
  float tA = A0 * iA + A1 * iB;  // this lane's 2 heads, even channel
  float tB = B0 * iA + B1 * iB;  // odd channel
  float sA = tA + __shfl_xor(tA, 32, 64);  // all 4 heads
  float sB = tB + __shfl_xor(tB, 32, 64);
  int cA = 2 * (lane & 31);
  float2 bv = *(const float2*)(bias + cA);
  float oA = 0.25f * sA + bv.x;
  float oB = 0.25f * sB + bv.y;
  float mu = wave_sum(oA + oB) * (1.f / 128.f);   // duplicated halves -> /128
  float dA = oA - mu, dB = oB - mu;
  float var = wave_sum(dA * dA + dB * dB) * (1.f / 128.f);
  float rinv = rsqrtf(var + 1e-5f);
  float2 gv = *(const float2*)(g + cA);
  float2 bbv = *(const float2*)(b + cA);
  float rA = fmaxf(dA * rinv * gv.x + bbv.x, 0.f);
  float rB = fmaxf(dB * rinv * gv.y + bbv.y, 0.f);
  float* hp = h + (size_t)n * 64 + cA;
  if (doRes) { float2 hv = *(const float2*)hp; rA += hv.x; rB += hv.y; }
  if (lo32) { float2 o2; o2.x = rA; o2.y = rB; *(float2*)hp = o2; }
}

__global__ void k_zero(float* __restrict__ p, int n) {
  int t = blockIdx.x * blockDim.x + threadIdx.x;
  if (t < n) p[t] = 0.f;
}

__global__ void k_pool(const float* __restrict__ h, const int* __restrict__ batch,
                       float* __restrict__ pool, float* __restrict__ cnt, int N)
{
  int t = blockIdx.x * blockDim.x + threadIdx.x;
  if (t >= N * 64) return;
  int n = t >> 6, c = t & 63;
  int gid = batch[n];
  atomicAdd(&pool[gid * 64 + c], h[t]);
  if (c == 0) atomicAdd(&cnt[gid], 1.f);
}

__global__ void k_out(const float* __restrict__ pool, const float* __restrict__ cnt,
                      const float* __restrict__ Wout, const float* __restrict__ bout,
                      float* __restrict__ out, int NG)
{
  int t = blockIdx.x * blockDim.x + threadIdx.x;
  if (t >= NG * 32) return;
  int gid = t >> 5, j = t & 31;
  float s = 0.f;
#pragma unroll
  for (int c = 0; c < 64; ++c) s = fmaf(pool[gid * 64 + c], Wout[c * 32 + j], s);
  out[t] = s / fmaxf(cnt[gid], 1.f) + bout[j];
}

extern "C" void kernel_launch(void* const* d_in, const int* in_sizes, int n_in,
                              void* d_out, int out_size, void* d_ws, size_t ws_size,
                              hipStream_t stream) {
  const float* x    = (const float*)d_in[0];
  const int*   ei   = (const int*)d_in[1];
  const int*   batch= (const int*)d_in[2];
  const float* Win  = (const float*)d_in[3];
  const float* bin  = (const float*)d_in[4];
  const float* Wgat = (const float*)d_in[5];
  const float* asrc = (const float*)d_in[6];
  const float* adst = (const float*)d_in[7];
  const float* bgat = (const float*)d_in[8];
  const float* lng  = (const float*)d_in[9];
  const float* lnb  = (const float*)d_in[10];
  const float* Wout = (const float*)d_in[11];
  const float* bout = (const float*)d_in[12];
  float* out = (float*)d_out;

  int N  = in_sizes[0] / 32;
  int E  = in_sizes[1] / 2;
  int NG = out_size / 32;
  int L  = in_sizes[5] / (64 * 256);

  char* w = (char*)d_ws;
  unsigned short* xhb = (unsigned short*)w; w += (size_t)N * 256 * 2;
  float* h  = (float*)w;       w += (size_t)N * 64 * 4;
  float* als= (float*)w;       w += (size_t)N * 4 * 4;
  float* ald= (float*)w;       w += (size_t)N * 4 * 4;
  int* rowstart = (int*)w;     w += (size_t)(N + 1) * 4;
  int* counter  = (int*)w;     w += (size_t)N * 4;
  int* srcs     = (int*)w;     w += (size_t)(E + N) * 4;
  float* pool   = (float*)w;   w += (size_t)NG * 64 * 4;
  float* cnt    = (float*)w;   w += (size_t)NG * 4;

  const int* esrc = ei;       // edge_index[0]
  const int* edst = ei + E;   // edge_index[1]

  // input layer
  k_input<<<(N + 63) / 64, 256, 0, stream>>>(x, Win, bin, h, N);

  // CSR build (dst-grouped), self-loops included via deg init = 1
  k_set1<<<(N + 255) / 256, 256, 0, stream>>>(counter, N);
  k_count<<<(E + 255) / 256, 256, 0, stream>>>(edst, counter, E);
  k_scan<<<1, 1024, 0, stream>>>(counter, rowstart, N);
  k_fill<<<(E + N + 255) / 256, 256, 0, stream>>>(esrc, edst, counter, srcs, E, N);

  for (int i = 0; i < L; ++i) {
    k_xh<<<(N + 63) / 64, 256, 0, stream>>>(h, Wgat + (size_t)i * 64 * 256,
        asrc + i * 256, adst + i * 256, xhb, als, ald, N);
    k_agg<<<(N + 3) / 4, 256, 0, stream>>>(xhb, als, ald, rowstart, srcs,
        bgat + i * 64, lng + i * 64, lnb + i * 64, h, N, i > 0 ? 1 : 0);
  }

  // mean pool + output GEMM
  k_zero<<<(NG * 65 + 255) / 256, 256, 0, stream>>>(pool, NG * 65);
  k_pool<<<(N * 64 + 255) / 256, 256, 0, stream>>>(h, batch, pool, cnt, N);
  k_out<<<(NG * 32 + 255) / 256, 256, 0, stream>>>(pool, cnt, Wout, bout, out, NG);
}

// Round 5
// 598.032 us; speedup vs baseline: 2.9016x; 1.2063x over previous
//
#include <hip/hip_runtime.h>
#include <hip/hip_bf16.h>

// GAT GNN: N=50000 nodes, E=800000 edges (+N self loops), C=64, H=4, L=3, NG=256
// R4: replace atomic k_pool/k_zero/k_out with fused k_graph (batch is sorted ->
//     per-graph contiguous ranges via binary search; block-local reduce + GEMM).

__device__ __forceinline__ float wave_sum(float v) {
#pragma unroll
  for (int d = 32; d > 0; d >>= 1) v += __shfl_xor(v, d, 64);
  return v;
}
__device__ __forceinline__ float wave_max(float v) {
#pragma unroll
  for (int d = 32; d > 0; d >>= 1) v = fmaxf(v, __shfl_xor(v, d, 64));
  return v;
}
__device__ __forceinline__ float lrelu02(float v) { return fmaxf(v, 0.2f * v); }

__device__ __forceinline__ unsigned short f2bf(float f) {
  unsigned u = __float_as_uint(f);
  return (unsigned short)((u + 0x7fffu + ((u >> 16) & 1u)) >> 16);
}

// h = relu(x @ W_in + b_in); x [N,32] staged in LDS, broadcast reads + FMA.
__global__ __launch_bounds__(256, 4) void k_input(const float* __restrict__ x,
    const float* __restrict__ Win, const float* __restrict__ bin,
    float* __restrict__ h, int N)
{
  __shared__ float xs[64 * 32];
  int tid = threadIdx.x;
  int lane = tid & 63, wid = tid >> 6;
  int n0 = blockIdx.x * 64;
  int nrows = N - n0; if (nrows > 64) nrows = 64;
  {
    const float4* srcp = (const float4*)(x + (size_t)n0 * 32);
    float4* dstp = (float4*)xs;
    for (int i = tid; i < nrows * 8; i += 256) dstp[i] = srcp[i];
  }
  float wreg[32];
#pragma unroll
  for (int k = 0; k < 32; ++k) wreg[k] = Win[k * 64 + lane];
  float bv = bin[lane];
  __syncthreads();
  int nbeg = wid * 16;
  int nlim = nbeg + 16; if (nlim > nrows) nlim = nrows;
  for (int nn = nbeg; nn < nlim; ++nn) {
    const float* r = xs + nn * 32;
    float c0 = 0.f, c1 = 0.f;
#pragma unroll
    for (int k = 0; k < 32; k += 2) {
      c0 = fmaf(r[k],     wreg[k],     c0);
      c1 = fmaf(r[k + 1], wreg[k + 1], c1);
    }
    h[(size_t)(n0 + nn) * 64 + lane] = fmaxf(c0 + c1 + bv, 0.f);
  }
}

__global__ void k_set1(int* __restrict__ p, int n) {
  int t = blockIdx.x * blockDim.x + threadIdx.x;
  if (t < n) p[t] = 1;
}

__global__ void k_count(const int* __restrict__ dst, int* __restrict__ cnt, int E) {
  int t = blockIdx.x * blockDim.x + threadIdx.x;
  if (t < E) atomicAdd(&cnt[dst[t]], 1);
}

// Single-block exclusive scan of counter[0..N) -> rowstart[0..N].
__global__ __launch_bounds__(1024) void k_scan(int* __restrict__ counter,
                                               int* __restrict__ rowstart, int N)
{
  __shared__ int wsums[16];
  __shared__ int s_carry;
  int tid = threadIdx.x, lane = tid & 63, wid = tid >> 6;
  if (tid == 0) s_carry = 0;
  __syncthreads();
  for (int base = 0; base < N; base += 1024) {
    int i = base + tid;
    int v = (i < N) ? counter[i] : 0;
    int x = v;
#pragma unroll
    for (int d = 1; d < 64; d <<= 1) {
      int y = __shfl_up(x, d, 64);
      if (lane >= d) x += y;
    }
    if (lane == 63) wsums[wid] = x;
    __syncthreads();
    if (wid == 0) {
      int s = (lane < 16) ? wsums[lane] : 0;
#pragma unroll
      for (int d = 1; d < 16; d <<= 1) {
        int y = __shfl_up(s, d, 64);
        if (lane >= d) s += y;
      }
      if (lane < 16) wsums[lane] = s;
    }
    __syncthreads();
    int carry = s_carry;
    int woff = (wid > 0) ? wsums[wid - 1] : 0;
    int excl = carry + woff + (x - v);
    if (i < N) { rowstart[i] = excl; counter[i] = excl; }
    int total = wsums[15];
    __syncthreads();
    if (tid == 0) s_carry = carry + total;
    __syncthreads();
  }
  if (threadIdx.x == 0) rowstart[N] = s_carry;
}

__global__ void k_fill(const int* __restrict__ src, const int* __restrict__ dst,
                       int* __restrict__ counter, int* __restrict__ srcs, int E, int N)
{
  int t = blockIdx.x * blockDim.x + threadIdx.x;
  if (t >= E + N) return;
  int s, d;
  if (t < E) { s = src[t]; d = dst[t]; } else { s = t - E; d = s; }
  int pos = atomicAdd(&counter[d], 1);
  srcs[pos] = s;
}

// xh[n,256] = h[n,:] @ Wg[64,256] (bf16 out); h-tile staged in LDS, broadcast
// ds_read + FMA; W column in 64 VGPRs; als/ald via wave reductions.
__global__ __launch_bounds__(256, 4) void k_xh(const float* __restrict__ h,
    const float* __restrict__ Wg, const float* __restrict__ asrc,
    const float* __restrict__ adst, unsigned short* __restrict__ xhb,
    float* __restrict__ als, float* __restrict__ ald, int N)
{
  __shared__ float hs[64 * 64];
  int tid = threadIdx.x;
  int lane = tid & 63, wid = tid >> 6;
  int n0 = blockIdx.x * 64;
  int nrows = N - n0; if (nrows > 64) nrows = 64;
  {
    const float4* srcp = (const float4*)(h + (size_t)n0 * 64);
    float4* dstp = (float4*)hs;
    for (int i = tid; i < nrows * 16; i += 256) dstp[i] = srcp[i];
  }
  float wreg[64];
#pragma unroll
  for (int k = 0; k < 64; ++k) wreg[k] = Wg[k * 256 + tid];
  float avs = asrc[tid], avd = adst[tid];
  __syncthreads();
  int nn = 0;
  for (; nn + 1 < nrows; nn += 2) {
    const float* r0 = hs + nn * 64;
    const float* r1 = r0 + 64;
    float a0 = 0.f, b0 = 0.f, a1 = 0.f, b1 = 0.f;
#pragma unroll
    for (int k = 0; k < 64; k += 2) {
      a0 = fmaf(r0[k],     wreg[k],     a0);
      b0 = fmaf(r0[k + 1], wreg[k + 1], b0);
      a1 = fmaf(r1[k],     wreg[k],     a1);
      b1 = fmaf(r1[k + 1], wreg[k + 1], b1);
    }
    float x0 = a0 + b0, x1 = a1 + b1;
    int n = n0 + nn;
    xhb[(size_t)n * 256 + tid] = f2bf(x0);
    xhb[(size_t)(n + 1) * 256 + tid] = f2bf(x1);
    float s0 = wave_sum(x0 * avs), d0 = wave_sum(x0 * avd);
    float s1 = wave_sum(x1 * avs), d1 = wave_sum(x1 * avd);
    if (lane == 0) {
      als[n * 4 + wid] = s0;       ald[n * 4 + wid] = d0;
      als[(n + 1) * 4 + wid] = s1; ald[(n + 1) * 4 + wid] = d1;
    }
  }
  if (nn < nrows) {
    const float* r0 = hs + nn * 64;
    float a0 = 0.f, b0 = 0.f;
#pragma unroll
    for (int k = 0; k < 64; k += 2) {
      a0 = fmaf(r0[k],     wreg[k],     a0);
      b0 = fmaf(r0[k + 1], wreg[k + 1], b0);
    }
    float x0 = a0 + b0;
    int n = n0 + nn;
    xhb[(size_t)n * 256 + tid] = f2bf(x0);
    float s0 = wave_sum(x0 * avs), d0 = wave_sum(x0 * avd);
    if (lane == 0) { als[n * 4 + wid] = s0; ald[n * 4 + wid] = d0; }
  }
}

// One wave per node. Edge-parallel softmax: lane e handles edge beg+e
// (coalesced srcs, 16B als gather, lrelu, wave-max, exp); p[4]+src staged in
// per-wave LDS. Serial gather loop: broadcast ds_read p/s + 2 dword loads/lane
// (lane owns 2 channels x 2 heads of the 512B bf16 row) + 4 FMA.
__global__ __launch_bounds__(256) void k_agg(const unsigned short* __restrict__ xhb,
    const float* __restrict__ als, const float* __restrict__ ald,
    const int* __restrict__ rowstart, const int* __restrict__ srcs,
    const float* __restrict__ bias, const float* __restrict__ g,
    const float* __restrict__ b, float* __restrict__ h, int N, int doRes)
{
  __shared__ float4 pb[4][64];
  __shared__ int sb[4][64];
  int lane = threadIdx.x & 63;
  int wid = threadIdx.x >> 6;
  int n = blockIdx.x * 4 + wid;
  if (n >= N) return;
  int beg = rowstart[n], end = rowstart[n + 1];
  int deg = end - beg;
  const float4 adv = *(const float4*)(ald + (size_t)n * 4);
  const unsigned* xu = (const unsigned*)xhb;
  bool lo32 = (lane < 32);

  float l0 = 0.f, l1 = 0.f, l2 = 0.f, l3 = 0.f;
  float A0 = 0.f, B0 = 0.f, A1 = 0.f, B1 = 0.f;

  if (deg <= 64) {
    int e = beg + lane;
    int ce = (e < end) ? e : (end - 1);
    int s = srcs[ce];
    float4 av = *(const float4*)(als + (size_t)s * 4);
    float e0 = lrelu02(av.x + adv.x);
    float e1 = lrelu02(av.y + adv.y);
    float e2 = lrelu02(av.z + adv.z);
    float e3 = lrelu02(av.w + adv.w);
    bool act = (e < end);
    float m0 = wave_max(act ? e0 : -1e30f);
    float m1 = wave_max(act ? e1 : -1e30f);
    float m2 = wave_max(act ? e2 : -1e30f);
    float m3 = wave_max(act ? e3 : -1e30f);
    float p0 = act ? __expf(e0 - m0) : 0.f;
    float p1 = act ? __expf(e1 - m1) : 0.f;
    float p2 = act ? __expf(e2 - m2) : 0.f;
    float p3 = act ? __expf(e3 - m3) : 0.f;
    l0 = p0; l1 = p1; l2 = p2; l3 = p3;
    pb[wid][lane] = make_float4(p0, p1, p2, p3);
    sb[wid][lane] = s;
    for (int j = 0; j < deg; ++j) {
      float4 p = pb[wid][j];
      int sj = sb[wid][j];
      const unsigned* row = xu + (size_t)sj * 128;
      unsigned u0 = row[lane];
      unsigned u1 = row[64 + lane];
      float pA = lo32 ? p.x : p.y;
      float pB = lo32 ? p.z : p.w;
      A0 = fmaf(pA, __uint_as_float(u0 << 16), A0);
      B0 = fmaf(pA, __uint_as_float(u0 & 0xffff0000u), B0);
      A1 = fmaf(pB, __uint_as_float(u1 << 16), A1);
      B1 = fmaf(pB, __uint_as_float(u1 & 0xffff0000u), B1);
    }
  } else {
    float m0 = -1e30f, m1 = -1e30f, m2 = -1e30f, m3 = -1e30f;
    for (int base = beg; base < end; base += 64) {
      int e = base + lane;
      int ce = (e < end) ? e : (end - 1);
      int s = srcs[ce];
      float4 av = *(const float4*)(als + (size_t)s * 4);
      bool act = (e < end);
      m0 = fmaxf(m0, act ? lrelu02(av.x + adv.x) : -1e30f);
      m1 = fmaxf(m1, act ? lrelu02(av.y + adv.y) : -1e30f);
      m2 = fmaxf(m2, act ? lrelu02(av.z + adv.z) : -1e30f);
      m3 = fmaxf(m3, act ? lrelu02(av.w + adv.w) : -1e30f);
    }
    m0 = wave_max(m0); m1 = wave_max(m1); m2 = wave_max(m2); m3 = wave_max(m3);
    for (int base = beg; base < end; base += 64) {
      int e = base + lane;
      int ce = (e < end) ? e : (end - 1);
      int s = srcs[ce];
      float4 av = *(const float4*)(als + (size_t)s * 4);
      bool act = (e < end);
      float p0 = act ? __expf(lrelu02(av.x + adv.x) - m0) : 0.f;
      float p1 = act ? __expf(lrelu02(av.y + adv.y) - m1) : 0.f;
      float p2 = act ? __expf(lrelu02(av.z + adv.z) - m2) : 0.f;
      float p3 = act ? __expf(lrelu02(av.w + adv.w) - m3) : 0.f;
      l0 += p0; l1 += p1; l2 += p2; l3 += p3;
      pb[wid][lane] = make_float4(p0, p1, p2, p3);
      sb[wid][lane] = s;
      int cnt = end - base; if (cnt > 64) cnt = 64;
      for (int j = 0; j < cnt; ++j) {
        float4 p = pb[wid][j];
        int sj = sb[wid][j];
        const unsigned* row = xu + (size_t)sj * 128;
        unsigned u0 = row[lane];
        unsigned u1 = row[64 + lane];
        float pA = lo32 ? p.x : p.y;
        float pB = lo32 ? p.z : p.w;
        A0 = fmaf(pA, __uint_as_float(u0 << 16), A0);
        B0 = fmaf(pA, __uint_as_float(u0 & 0xffff0000u), B0);
        A1 = fmaf(pB, __uint_as_float(u1 << 16), A1);
        B1 = fmaf(pB, __uint_as_float(u1 & 0xffff0000u), B1);
      }
    }
  }

  l0 = wave_sum(l0); l1 = wave_sum(l1); l2 = wave_sum(l2); l3 = wave_sum(l3);
  float i0 = 1.f / (l0 + 1e-16f), i1 = 1.f / (l1 + 1e-16f);
  float i2 = 1.f / (l2 + 1e-16f), i3 = 1.f / (l3 + 1e-16f);
  float iA = lo32 ? i0 : i1;
  float iB = lo32 ? i2 : i3;
  float tA = A0 * iA + A1 * iB;
  float tB = B0 * iA + B1 * iB;
  float sA = tA + __shfl_xor(tA, 32, 64);
  float sB = tB + __shfl_xor(tB, 32, 64);
  int cA = 2 * (lane & 31);
  float2 bv = *(const float2*)(bias + cA);
  float oA = 0.25f * sA + bv.x;
  float oB = 0.25f * sB + bv.y;
  float mu = wave_sum(oA + oB) * (1.f / 128.f);
  float dA = oA - mu, dB = oB - mu;
  float var = wave_sum(dA * dA + dB * dB) * (1.f / 128.f);
  float rinv = rsqrtf(var + 1e-5f);
  float2 gv = *(const float2*)(g + cA);
  float2 bbv = *(const float2*)(b + cA);
  float rA = fmaxf(dA * rinv * gv.x + bbv.x, 0.f);
  float rB = fmaxf(dB * rinv * gv.y + bbv.y, 0.f);
  float* hp = h + (size_t)n * 64 + cA;
  if (doRes) { float2 hv = *(const float2*)hp; rA += hv.x; rB += hv.y; }
  if (lo32) { float2 o2; o2.x = rA; o2.y = rB; *(float2*)hp = o2; }
}

// Fused global_mean_pool + output GEMM. batch sorted -> graph g occupies a
// contiguous node range found by binary search. Block per graph: 4 waves
// stride rows (lane = channel), LDS cross-wave reduce, then 64x32 GEMM.
__global__ __launch_bounds__(256) void k_graph(const float* __restrict__ h,
    const int* __restrict__ batch, const float* __restrict__ Wout,
    const float* __restrict__ bout, float* __restrict__ out, int N)
{
  __shared__ float sm[4][64];
  int g = blockIdx.x;
  int tid = threadIdx.x, lane = tid & 63, wid = tid >> 6;
  int lo = 0, hi = N;
  while (lo < hi) { int mid = (lo + hi) >> 1; if (batch[mid] < g) lo = mid + 1; else hi = mid; }
  int start = lo;
  hi = N;
  while (lo < hi) { int mid = (lo + hi) >> 1; if (batch[mid] < g + 1) lo = mid + 1; else hi = mid; }
  int end = lo;
  float acc = 0.f;
  for (int n = start + wid; n < end; n += 4) acc += h[(size_t)n * 64 + lane];
  sm[wid][lane] = acc;
  __syncthreads();
  if (wid == 0) {
    float s = sm[0][lane] + sm[1][lane] + sm[2][lane] + sm[3][lane];
    float cf = (float)(end - start);
    sm[0][lane] = s / fmaxf(cf, 1.f);
  }
  __syncthreads();
  if (tid < 32) {
    float s = 0.f;
#pragma unroll
    for (int c = 0; c < 64; ++c) s = fmaf(sm[0][c], Wout[c * 32 + tid], s);
    out[g * 32 + tid] = s + bout[tid];
  }
}

extern "C" void kernel_launch(void* const* d_in, const int* in_sizes, int n_in,
                              void* d_out, int out_size, void* d_ws, size_t ws_size,
                              hipStream_t stream) {
  const float* x    = (const float*)d_in[0];
  const int*   ei   = (const int*)d_in[1];
  const int*   batch= (const int*)d_in[2];
  const float* Win  = (const float*)d_in[3];
  const float* bin  = (const float*)d_in[4];
  const float* Wgat = (const float*)d_in[5];
  const float* asrc = (const float*)d_in[6];
  const float* adst = (const float*)d_in[7];
  const float* bgat = (const float*)d_in[8];
  const float* lng  = (const float*)d_in[9];
  const float* lnb  = (const float*)d_in[10];
  const float* Wout = (const float*)d_in[11];
  const float* bout = (const float*)d_in[12];
  float* out = (float*)d_out;

  int N  = in_sizes[0] / 32;
  int E  = in_sizes[1] / 2;
  int NG = out_size / 32;
  int L  = in_sizes[5] / (64 * 256);

  char* w = (char*)d_ws;
  unsigned short* xhb = (unsigned short*)w; w += (size_t)N * 256 * 2;
  float* h  = (float*)w;       w += (size_t)N * 64 * 4;
  float* als= (float*)w;       w += (size_t)N * 4 * 4;
  float* ald= (float*)w;       w += (size_t)N * 4 * 4;
  int* rowstart = (int*)w;     w += (size_t)(N + 1) * 4;
  int* counter  = (int*)w;     w += (size_t)N * 4;
  int* srcs     = (int*)w;     w += (size_t)(E + N) * 4;

  const int* esrc = ei;       // edge_index[0]
  const int* edst = ei + E;   // edge_index[1]

  // input layer
  k_input<<<(N + 63) / 64, 256, 0, stream>>>(x, Win, bin, h, N);

  // CSR build (dst-grouped), self-loops included via deg init = 1
  k_set1<<<(N + 255) / 256, 256, 0, stream>>>(counter, N);
  k_count<<<(E + 255) / 256, 256, 0, stream>>>(edst, counter, E);
  k_scan<<<1, 1024, 0, stream>>>(counter, rowstart, N);
  k_fill<<<(E + N + 255) / 256, 256, 0, stream>>>(esrc, edst, counter, srcs, E, N);

  for (int i = 0; i < L; ++i) {
    k_xh<<<(N + 63) / 64, 256, 0, stream>>>(h, Wgat + (size_t)i * 64 * 256,
        asrc + i * 256, adst + i * 256, xhb, als, ald, N);
    k_agg<<<(N + 3) / 4, 256, 0, stream>>>(xhb, als, ald, rowstart, srcs,
        bgat + i * 64, lng + i * 64, lnb + i * 64, h, N, i > 0 ? 1 : 0);
  }

  // fused mean pool + output GEMM (no atomics; batch is sorted)
  k_graph<<<NG, 256, 0, stream>>>(h, batch, Wout, bout, out, N);
}

// Round 6
// 589.216 us; speedup vs baseline: 2.9450x; 1.0150x over previous
//
#include <hip/hip_runtime.h>
#include <hip/hip_bf16.h>

// GAT GNN: N=50000 nodes, E=800000 edges (+N self loops), C=64, H=4, L=3, NG=256
// R5: k_xh 32-node tiles (2x grid), float4 LDS reads, 8 FMA : 2 ds_read_b128,
//     launch_bounds(256,5); k_agg gather loop unrolled x2 (4 loads in flight).

__device__ __forceinline__ float wave_sum(float v) {
#pragma unroll
  for (int d = 32; d > 0; d >>= 1) v += __shfl_xor(v, d, 64);
  return v;
}
__device__ __forceinline__ float wave_max(float v) {
#pragma unroll
  for (int d = 32; d > 0; d >>= 1) v = fmaxf(v, __shfl_xor(v, d, 64));
  return v;
}
__device__ __forceinline__ float lrelu02(float v) { return fmaxf(v, 0.2f * v); }

__device__ __forceinline__ unsigned short f2bf(float f) {
  unsigned u = __float_as_uint(f);
  return (unsigned short)((u + 0x7fffu + ((u >> 16) & 1u)) >> 16);
}

// h = relu(x @ W_in + b_in); x [N,32] staged in LDS, broadcast reads + FMA.
__global__ __launch_bounds__(256, 4) void k_input(const float* __restrict__ x,
    const float* __restrict__ Win, const float* __restrict__ bin,
    float* __restrict__ h, int N)
{
  __shared__ float xs[64 * 32];
  int tid = threadIdx.x;
  int lane = tid & 63, wid = tid >> 6;
  int n0 = blockIdx.x * 64;
  int nrows = N - n0; if (nrows > 64) nrows = 64;
  {
    const float4* srcp = (const float4*)(x + (size_t)n0 * 32);
    float4* dstp = (float4*)xs;
    for (int i = tid; i < nrows * 8; i += 256) dstp[i] = srcp[i];
  }
  float wreg[32];
#pragma unroll
  for (int k = 0; k < 32; ++k) wreg[k] = Win[k * 64 + lane];
  float bv = bin[lane];
  __syncthreads();
  int nbeg = wid * 16;
  int nlim = nbeg + 16; if (nlim > nrows) nlim = nrows;
  for (int nn = nbeg; nn < nlim; ++nn) {
    const float4* r = (const float4*)(xs + nn * 32);
    float c0 = 0.f, c1 = 0.f;
#pragma unroll
    for (int k4 = 0; k4 < 8; ++k4) {
      float4 q = r[k4];
      int k = k4 * 4;
      c0 = fmaf(q.x, wreg[k],     c0);
      c1 = fmaf(q.y, wreg[k + 1], c1);
      c0 = fmaf(q.z, wreg[k + 2], c0);
      c1 = fmaf(q.w, wreg[k + 3], c1);
    }
    h[(size_t)(n0 + nn) * 64 + lane] = fmaxf(c0 + c1 + bv, 0.f);
  }
}

__global__ void k_set1(int* __restrict__ p, int n) {
  int t = blockIdx.x * blockDim.x + threadIdx.x;
  if (t < n) p[t] = 1;
}

__global__ void k_count(const int* __restrict__ dst, int* __restrict__ cnt, int E) {
  int t = blockIdx.x * blockDim.x + threadIdx.x;
  if (t < E) atomicAdd(&cnt[dst[t]], 1);
}

// Single-block exclusive scan of counter[0..N) -> rowstart[0..N].
__global__ __launch_bounds__(1024) void k_scan(int* __restrict__ counter,
                                               int* __restrict__ rowstart, int N)
{
  __shared__ int wsums[16];
  __shared__ int s_carry;
  int tid = threadIdx.x, lane = tid & 63, wid = tid >> 6;
  if (tid == 0) s_carry = 0;
  __syncthreads();
  for (int base = 0; base < N; base += 1024) {
    int i = base + tid;
    int v = (i < N) ? counter[i] : 0;
    int x = v;
#pragma unroll
    for (int d = 1; d < 64; d <<= 1) {
      int y = __shfl_up(x, d, 64);
      if (lane >= d) x += y;
    }
    if (lane == 63) wsums[wid] = x;
    __syncthreads();
    if (wid == 0) {
      int s = (lane < 16) ? wsums[lane] : 0;
#pragma unroll
      for (int d = 1; d < 16; d <<= 1) {
        int y = __shfl_up(s, d, 64);
        if (lane >= d) s += y;
      }
      if (lane < 16) wsums[lane] = s;
    }
    __syncthreads();
    int carry = s_carry;
    int woff = (wid > 0) ? wsums[wid - 1] : 0;
    int excl = carry + woff + (x - v);
    if (i < N) { rowstart[i] = excl; counter[i] = excl; }
    int total = wsums[15];
    __syncthreads();
    if (tid == 0) s_carry = carry + total;
    __syncthreads();
  }
  if (threadIdx.x == 0) rowstart[N] = s_carry;
}

__global__ void k_fill(const int* __restrict__ src, const int* __restrict__ dst,
                       int* __restrict__ counter, int* __restrict__ srcs, int E, int N)
{
  int t = blockIdx.x * blockDim.x + threadIdx.x;
  if (t >= E + N) return;
  int s, d;
  if (t < E) { s = src[t]; d = dst[t]; } else { s = t - E; d = s; }
  int pos = atomicAdd(&counter[d], 1);
  srcs[pos] = s;
}

// xh[n,256] = h[n,:] @ Wg[64,256] (bf16 out); 32-node tile staged in LDS,
// float4 broadcast reads (8 FMA : 2 ds_read_b128, 4 chains); W col in VGPRs.
__global__ __launch_bounds__(256, 5) void k_xh(const float* __restrict__ h,
    const float* __restrict__ Wg, const float* __restrict__ asrc,
    const float* __restrict__ adst, unsigned short* __restrict__ xhb,
    float* __restrict__ als, float* __restrict__ ald, int N)
{
  __shared__ float hs[32 * 64];
  int tid = threadIdx.x;
  int lane = tid & 63, wid = tid >> 6;
  int n0 = blockIdx.x * 32;
  int nrows = N - n0; if (nrows > 32) nrows = 32;
  {
    const float4* srcp = (const float4*)(h + (size_t)n0 * 64);
    float4* dstp = (float4*)hs;
    for (int i = tid; i < nrows * 16; i += 256) dstp[i] = srcp[i];
  }
  float wreg[64];
#pragma unroll
  for (int k = 0; k < 64; ++k) wreg[k] = Wg[k * 256 + tid];
  float avs = asrc[tid], avd = adst[tid];
  __syncthreads();
  const float4* hs4 = (const float4*)hs;
  int nn = 0;
  for (; nn + 1 < nrows; nn += 2) {
    const float4* r0 = hs4 + nn * 16;
    const float4* r1 = r0 + 16;
    float a0 = 0.f, b0 = 0.f, a1 = 0.f, b1 = 0.f;
#pragma unroll
    for (int k4 = 0; k4 < 16; ++k4) {
      float4 q0 = r0[k4];
      float4 q1 = r1[k4];
      int k = k4 * 4;
      a0 = fmaf(q0.x, wreg[k],     a0);
      b0 = fmaf(q0.y, wreg[k + 1], b0);
      a0 = fmaf(q0.z, wreg[k + 2], a0);
      b0 = fmaf(q0.w, wreg[k + 3], b0);
      a1 = fmaf(q1.x, wreg[k],     a1);
      b1 = fmaf(q1.y, wreg[k + 1], b1);
      a1 = fmaf(q1.z, wreg[k + 2], a1);
      b1 = fmaf(q1.w, wreg[k + 3], b1);
    }
    float x0 = a0 + b0, x1 = a1 + b1;
    int n = n0 + nn;
    xhb[(size_t)n * 256 + tid] = f2bf(x0);
    xhb[(size_t)(n + 1) * 256 + tid] = f2bf(x1);
    float s0 = wave_sum(x0 * avs), d0 = wave_sum(x0 * avd);
    float s1 = wave_sum(x1 * avs), d1 = wave_sum(x1 * avd);
    if (lane == 0) {
      als[n * 4 + wid] = s0;       ald[n * 4 + wid] = d0;
      als[(n + 1) * 4 + wid] = s1; ald[(n + 1) * 4 + wid] = d1;
    }
  }
  if (nn < nrows) {
    const float4* r0 = hs4 + nn * 16;
    float a0 = 0.f, b0 = 0.f;
#pragma unroll
    for (int k4 = 0; k4 < 16; ++k4) {
      float4 q0 = r0[k4];
      int k = k4 * 4;
      a0 = fmaf(q0.x, wreg[k],     a0);
      b0 = fmaf(q0.y, wreg[k + 1], b0);
      a0 = fmaf(q0.z, wreg[k + 2], a0);
      b0 = fmaf(q0.w, wreg[k + 3], b0);
    }
    float x0 = a0 + b0;
    int n = n0 + nn;
    xhb[(size_t)n * 256 + tid] = f2bf(x0);
    float s0 = wave_sum(x0 * avs), d0 = wave_sum(x0 * avd);
    if (lane == 0) { als[n * 4 + wid] = s0; ald[n * 4 + wid] = d0; }
  }
}

// One wave per node. Edge-parallel softmax; gather loop unrolled x2 with
// paired loads (4 VMEM in flight) to hide L2/L3 latency.
__global__ __launch_bounds__(256) void k_agg(const unsigned short* __restrict__ xhb,
    const float* __restrict__ als, const float* __restrict__ ald,
    const int* __restrict__ rowstart, const int* __restrict__ srcs,
    const float* __restrict__ bias, const float* __restrict__ g,
    const float* __restrict__ b, float* __restrict__ h, int N, int doRes)
{
  __shared__ float4 pb[4][64];
  __shared__ int sb[4][64];
  int lane = threadIdx.x & 63;
  int wid = threadIdx.x >> 6;
  int n = blockIdx.x * 4 + wid;
  if (n >= N) return;
  int beg = rowstart[n], end = rowstart[n + 1];
  int deg = end - beg;
  const float4 adv = *(const float4*)(ald + (size_t)n * 4);
  const unsigned* xu = (const unsigned*)xhb;
  bool lo32 = (lane < 32);

  float l0 = 0.f, l1 = 0.f, l2 = 0.f, l3 = 0.f;
  float A0 = 0.f, B0 = 0.f, A1 = 0.f, B1 = 0.f;

  if (deg <= 64) {
    int e = beg + lane;
    int ce = (e < end) ? e : (end - 1);
    int s = srcs[ce];
    float4 av = *(const float4*)(als + (size_t)s * 4);
    float e0 = lrelu02(av.x + adv.x);
    float e1 = lrelu02(av.y + adv.y);
    float e2 = lrelu02(av.z + adv.z);
    float e3 = lrelu02(av.w + adv.w);
    bool act = (e < end);
    float m0 = wave_max(act ? e0 : -1e30f);
    float m1 = wave_max(act ? e1 : -1e30f);
    float m2 = wave_max(act ? e2 : -1e30f);
    float m3 = wave_max(act ? e3 : -1e30f);
    float p0 = act ? __expf(e0 - m0) : 0.f;
    float p1 = act ? __expf(e1 - m1) : 0.f;
    float p2 = act ? __expf(e2 - m2) : 0.f;
    float p3 = act ? __expf(e3 - m3) : 0.f;
    l0 = p0; l1 = p1; l2 = p2; l3 = p3;
    pb[wid][lane] = make_float4(p0, p1, p2, p3);
    sb[wid][lane] = s;
    int j = 0;
    for (; j + 1 < deg; j += 2) {
      float4 pa = pb[wid][j];
      float4 pc = pb[wid][j + 1];
      int sa = sb[wid][j];
      int sc = sb[wid][j + 1];
      const unsigned* ra = xu + (size_t)sa * 128;
      const unsigned* rc = xu + (size_t)sc * 128;
      unsigned ua0 = ra[lane], ua1 = ra[64 + lane];
      unsigned uc0 = rc[lane], uc1 = rc[64 + lane];
      float pA = lo32 ? pa.x : pa.y;
      float pB = lo32 ? pa.z : pa.w;
      float qA = lo32 ? pc.x : pc.y;
      float qB = lo32 ? pc.z : pc.w;
      A0 = fmaf(pA, __uint_as_float(ua0 << 16), A0);
      B0 = fmaf(pA, __uint_as_float(ua0 & 0xffff0000u), B0);
      A1 = fmaf(pB, __uint_as_float(ua1 << 16), A1);
      B1 = fmaf(pB, __uint_as_float(ua1 & 0xffff0000u), B1);
      A0 = fmaf(qA, __uint_as_float(uc0 << 16), A0);
      B0 = fmaf(qA, __uint_as_float(uc0 & 0xffff0000u), B0);
      A1 = fmaf(qB, __uint_as_float(uc1 << 16), A1);
      B1 = fmaf(qB, __uint_as_float(uc1 & 0xffff0000u), B1);
    }
    if (j < deg) {
      float4 p = pb[wid][j];
      int sj = sb[wid][j];
      const unsigned* row = xu + (size_t)sj * 128;
      unsigned u0 = row[lane];
      unsigned u1 = row[64 + lane];
      float pA = lo32 ? p.x : p.y;
      float pB = lo32 ? p.z : p.w;
      A0 = fmaf(pA, __uint_as_float(u0 << 16), A0);
      B0 = fmaf(pA, __uint_as_float(u0 & 0xffff0000u), B0);
      A1 = fmaf(pB, __uint_as_float(u1 << 16), A1);
      B1 = fmaf(pB, __uint_as_float(u1 & 0xffff0000u), B1);
    }
  } else {
    float m0 = -1e30f, m1 = -1e30f, m2 = -1e30f, m3 = -1e30f;
    for (int base = beg; base < end; base += 64) {
      int e = base + lane;
      int ce = (e < end) ? e : (end - 1);
      int s = srcs[ce];
      float4 av = *(const float4*)(als + (size_t)s * 4);
      bool act = (e < end);
      m0 = fmaxf(m0, act ? lrelu02(av.x + adv.x) : -1e30f);
      m1 = fmaxf(m1, act ? lrelu02(av.y + adv.y) : -1e30f);
      m2 = fmaxf(m2, act ? lrelu02(av.z + adv.z) : -1e30f);
      m3 = fmaxf(m3, act ? lrelu02(av.w + adv.w) : -1e30f);
    }
    m0 = wave_max(m0); m1 = wave_max(m1); m2 = wave_max(m2); m3 = wave_max(m3);
    for (int base = beg; base < end; base += 64) {
      int e = base + lane;
      int ce = (e < end) ? e : (end - 1);
      int s = srcs[ce];
      float4 av = *(const float4*)(als + (size_t)s * 4);
      bool act = (e < end);
      float p0 = act ? __expf(lrelu02(av.x + adv.x) - m0) : 0.f;
      float p1 = act ? __expf(lrelu02(av.y + adv.y) - m1) : 0.f;
      float p2 = act ? __expf(lrelu02(av.z + adv.z) - m2) : 0.f;
      float p3 = act ? __expf(lrelu02(av.w + adv.w) - m3) : 0.f;
      l0 += p0; l1 += p1; l2 += p2; l3 += p3;
      pb[wid][lane] = make_float4(p0, p1, p2, p3);
      sb[wid][lane] = s;
      int cnt = end - base; if (cnt > 64) cnt = 64;
      for (int j = 0; j < cnt; ++j) {
        float4 p = pb[wid][j];
        int sj = sb[wid][j];
        const unsigned* row = xu + (size_t)sj * 128;
        unsigned u0 = row[lane];
        unsigned u1 = row[64 + lane];
        float pA = lo32 ? p.x : p.y;
        float pB = lo32 ? p.z : p.w;
        A0 = fmaf(pA, __uint_as_float(u0 << 16), A0);
        B0 = fmaf(pA, __uint_as_float(u0 & 0xffff0000u), B0);
        A1 = fmaf(pB, __uint_as_float(u1 << 16), A1);
        B1 = fmaf(pB, __uint_as_float(u1 & 0xffff0000u), B1);
      }
    }
  }

  l0 = wave_sum(l0); l1 = wave_sum(l1); l2 = wave_sum(l2); l3 = wave_sum(l3);
  float i0 = 1.f / (l0 + 1e-16f), i1 = 1.f / (l1 + 1e-16f);
  float i2 = 1.f / (l2 + 1e-16f), i3 = 1.f / (l3 + 1e-16f);
  float iA = lo32 ? i0 : i1;
  float iB = lo32 ? i2 : i3;
  float tA = A0 * iA + A1 * iB;
  float tB = B0 * iA + B1 * iB;
  float sA = tA + __shfl_xor(tA, 32, 64);
  float sB = tB + __shfl_xor(tB, 32, 64);
  int cA = 2 * (lane & 31);
  float2 bv = *(const float2*)(bias + cA);
  float oA = 0.25f * sA + bv.x;
  float oB = 0.25f * sB + bv.y;
  float mu = wave_sum(oA + oB) * (1.f / 128.f);
  float dA = oA - mu, dB = oB - mu;
  float var = wave_sum(dA * dA + dB * dB) * (1.f / 128.f);
  float rinv = rsqrtf(var + 1e-5f);
  float2 gv = *(const float2*)(g + cA);
  float2 bbv = *(const float2*)(b + cA);
  float rA = fmaxf(dA * rinv * gv.x + bbv.x, 0.f);
  float rB = fmaxf(dB * rinv * gv.y + bbv.y, 0.f);
  float* hp = h + (size_t)n * 64 + cA;
  if (doRes) { float2 hv = *(const float2*)hp; rA += hv.x; rB += hv.y; }
  if (lo32) { float2 o2; o2.x = rA; o2.y = rB; *(float2*)hp = o2; }
}

// Fused global_mean_pool + output GEMM (batch sorted -> contiguous ranges).
__global__ __launch_bounds__(256) void k_graph(const float* __restrict__ h,
    const int* __restrict__ batch, const float* __restrict__ Wout,
    const float* __restrict__ bout, float* __restrict__ out, int N)
{
  __shared__ float sm[4][64];
  int g = blockIdx.x;
  int tid = threadIdx.x, lane = tid & 63, wid = tid >> 6;
  int lo = 0, hi = N;
  while (lo < hi) { int mid = (lo + hi) >> 1; if (batch[mid] < g) lo = mid + 1; else hi = mid; }
  int start = lo;
  hi = N;
  while (lo < hi) { int mid = (lo + hi) >> 1; if (batch[mid] < g + 1) lo = mid + 1; else hi = mid; }
  int end = lo;
  float acc = 0.f;
  for (int n = start + wid; n < end; n += 4) acc += h[(size_t)n * 64 + lane];
  sm[wid][lane] = acc;
  __syncthreads();
  if (wid == 0) {
    float s = sm[0][lane] + sm[1][lane] + sm[2][lane] + sm[3][lane];
    float cf = (float)(end - start);
    sm[0][lane] = s / fmaxf(cf, 1.f);
  }
  __syncthreads();
  if (tid < 32) {
    float s = 0.f;
#pragma unroll
    for (int c = 0; c < 64; ++c) s = fmaf(sm[0][c], Wout[c * 32 + tid], s);
    out[g * 32 + tid] = s + bout[tid];
  }
}

extern "C" void kernel_launch(void* const* d_in, const int* in_sizes, int n_in,
                              void* d_out, int out_size, void* d_ws, size_t ws_size,
                              hipStream_t stream) {
  const float* x    = (const float*)d_in[0];
  const int*   ei   = (const int*)d_in[1];
  const int*   batch= (const int*)d_in[2];
  const float* Win  = (const float*)d_in[3];
  const float* bin  = (const float*)d_in[4];
  const float* Wgat = (const float*)d_in[5];
  const float* asrc = (const float*)d_in[6];
  const float* adst = (const float*)d_in[7];
  const float* bgat = (const float*)d_in[8];
  const float* lng  = (const float*)d_in[9];
  const float* lnb  = (const float*)d_in[10];
  const float* Wout = (const float*)d_in[11];
  const float* bout = (const float*)d_in[12];
  float* out = (float*)d_out;

  int N  = in_sizes[0] / 32;
  int E  = in_sizes[1] / 2;
  int NG = out_size / 32;
  int L  = in_sizes[5] / (64 * 256);

  char* w = (char*)d_ws;
  unsigned short* xhb = (unsigned short*)w; w += (size_t)N * 256 * 2;
  float* h  = (float*)w;       w += (size_t)N * 64 * 4;
  float* als= (float*)w;       w += (size_t)N * 4 * 4;
  float* ald= (float*)w;       w += (size_t)N * 4 * 4;
  int* rowstart = (int*)w;     w += (size_t)(N + 1) * 4;
  int* counter  = (int*)w;     w += (size_t)N * 4;
  int* srcs     = (int*)w;     w += (size_t)(E + N) * 4;

  const int* esrc = ei;       // edge_index[0]
  const int* edst = ei + E;   // edge_index[1]

  // input layer
  k_input<<<(N + 63) / 64, 256, 0, stream>>>(x, Win, bin, h, N);

  // CSR build (dst-grouped), self-loops included via deg init = 1
  k_set1<<<(N + 255) / 256, 256, 0, stream>>>(counter, N);
  k_count<<<(E + 255) / 256, 256, 0, stream>>>(edst, counter, E);
  k_scan<<<1, 1024, 0, stream>>>(counter, rowstart, N);
  k_fill<<<(E + N + 255) / 256, 256, 0, stream>>>(esrc, edst, counter, srcs, E, N);

  for (int i = 0; i < L; ++i) {
    k_xh<<<(N + 31) / 32, 256, 0, stream>>>(h, Wgat + (size_t)i * 64 * 256,
        asrc + i * 256, adst + i * 256, xhb, als, ald, N);
    k_agg<<<(N + 3) / 4, 256, 0, stream>>>(xhb, als, ald, rowstart, srcs,
        bgat + i * 64, lng + i * 64, lnb + i * 64, h, N, i > 0 ? 1 : 0);
  }

  // fused mean pool + output GEMM (no atomics; batch is sorted)
  k_graph<<<NG, 256, 0, stream>>>(h, batch, Wout, bout, out, N);
}

// Round 7
// 457.562 us; speedup vs baseline: 3.7923x; 1.2877x over previous
//
#include <hip/hip_runtime.h>
#include <hip/hip_bf16.h>

// GAT GNN: N=50000 nodes, E=800000 edges (+N self loops), C=64, H=4, L=3, NG=256
// R6: k_xh -> MFMA (mfma_f32_16x16x32_bf16) with hi/lo bf16 split of h and W
//     (fp32-grade accuracy, 6 MFMA per 16x16 tile). W pre-packed into B-frag
//     order by k_wprep. No LDS/barriers in k_xh. k_agg unchanged from R5.

typedef __attribute__((__ext_vector_type__(8))) __bf16 bf16x8;
typedef __attribute__((__ext_vector_type__(4))) float f32x4;

__device__ __forceinline__ float wave_sum(float v) {
#pragma unroll
  for (int d = 32; d > 0; d >>= 1) v += __shfl_xor(v, d, 64);
  return v;
}
__device__ __forceinline__ float wave_max(float v) {
#pragma unroll
  for (int d = 32; d > 0; d >>= 1) v = fmaxf(v, __shfl_xor(v, d, 64));
  return v;
}
__device__ __forceinline__ float lrelu02(float v) { return fmaxf(v, 0.2f * v); }

__device__ __forceinline__ unsigned short f2bf(float f) {
  unsigned u = __float_as_uint(f);
  return (unsigned short)((u + 0x7fffu + ((u >> 16) & 1u)) >> 16);
}
__device__ __forceinline__ float bf2f(unsigned short s) {
  return __uint_as_float(((unsigned)s) << 16);
}

// h = relu(x @ W_in + b_in); x [N,32] staged in LDS, broadcast reads + FMA.
__global__ __launch_bounds__(256, 4) void k_input(const float* __restrict__ x,
    const float* __restrict__ Win, const float* __restrict__ bin,
    float* __restrict__ h, int N)
{
  __shared__ float xs[64 * 32];
  int tid = threadIdx.x;
  int lane = tid & 63, wid = tid >> 6;
  int n0 = blockIdx.x * 64;
  int nrows = N - n0; if (nrows > 64) nrows = 64;
  {
    const float4* srcp = (const float4*)(x + (size_t)n0 * 32);
    float4* dstp = (float4*)xs;
    for (int i = tid; i < nrows * 8; i += 256) dstp[i] = srcp[i];
  }
  float wreg[32];
#pragma unroll
  for (int k = 0; k < 32; ++k) wreg[k] = Win[k * 64 + lane];
  float bv = bin[lane];
  __syncthreads();
  int nbeg = wid * 16;
  int nlim = nbeg + 16; if (nlim > nrows) nlim = nrows;
  for (int nn = nbeg; nn < nlim; ++nn) {
    const float4* r = (const float4*)(xs + nn * 32);
    float c0 = 0.f, c1 = 0.f;
#pragma unroll
    for (int k4 = 0; k4 < 8; ++k4) {
      float4 q = r[k4];
      int k = k4 * 4;
      c0 = fmaf(q.x, wreg[k],     c0);
      c1 = fmaf(q.y, wreg[k + 1], c1);
      c0 = fmaf(q.z, wreg[k + 2], c0);
      c1 = fmaf(q.w, wreg[k + 3], c1);
    }
    h[(size_t)(n0 + nn) * 64 + lane] = fmaxf(c0 + c1 + bv, 0.f);
  }
}

__global__ void k_set1(int* __restrict__ p, int n) {
  int t = blockIdx.x * blockDim.x + threadIdx.x;
  if (t < n) p[t] = 1;
}

__global__ void k_count(const int* __restrict__ dst, int* __restrict__ cnt, int E) {
  int t = blockIdx.x * blockDim.x + threadIdx.x;
  if (t < E) atomicAdd(&cnt[dst[t]], 1);
}

// Single-block exclusive scan of counter[0..N) -> rowstart[0..N].
__global__ __launch_bounds__(1024) void k_scan(int* __restrict__ counter,
                                               int* __restrict__ rowstart, int N)
{
  __shared__ int wsums[16];
  __shared__ int s_carry;
  int tid = threadIdx.x, lane = tid & 63, wid = tid >> 6;
  if (tid == 0) s_carry = 0;
  __syncthreads();
  for (int base = 0; base < N; base += 1024) {
    int i = base + tid;
    int v = (i < N) ? counter[i] : 0;
    int x = v;
#pragma unroll
    for (int d = 1; d < 64; d <<= 1) {
      int y = __shfl_up(x, d, 64);
      if (lane >= d) x += y;
    }
    if (lane == 63) wsums[wid] = x;
    __syncthreads();
    if (wid == 0) {
      int s = (lane < 16) ? wsums[lane] : 0;
#pragma unroll
      for (int d = 1; d < 16; d <<= 1) {
        int y = __shfl_up(s, d, 64);
        if (lane >= d) s += y;
      }
      if (lane < 16) wsums[lane] = s;
    }
    __syncthreads();
    int carry = s_carry;
    int woff = (wid > 0) ? wsums[wid - 1] : 0;
    int excl = carry + woff + (x - v);
    if (i < N) { rowstart[i] = excl; counter[i] = excl; }
    int total = wsums[15];
    __syncthreads();
    if (tid == 0) s_carry = carry + total;
    __syncthreads();
  }
  if (threadIdx.x == 0) rowstart[N] = s_carry;
}

__global__ void k_fill(const int* __restrict__ src, const int* __restrict__ dst,
                       int* __restrict__ counter, int* __restrict__ srcs, int E, int N)
{
  int t = blockIdx.x * blockDim.x + threadIdx.x;
  if (t >= E + N) return;
  int s, d;
  if (t < E) { s = src[t]; d = dst[t]; } else { s = t - E; d = s; }
  int pos = atomicAdd(&counter[d], 1);
  srcs[pos] = s;
}

// Pack Wgat[L][64][256] into MFMA B-fragment order, hi/lo bf16 split.
// Index: ((layer*32 + tile*2 + q)*64 + lane)*8 + j  holds W[k][c] with
// k = q*32 + (lane>>4)*8 + j, c = tile*16 + (lane&15).
__global__ void k_wprep(const float* __restrict__ Wg, unsigned short* __restrict__ whi,
                        unsigned short* __restrict__ wlo, int L)
{
  int t = blockIdx.x * blockDim.x + threadIdx.x;
  if (t >= L * 2048) return;
  int layer = t >> 11;
  int rem = t & 2047;
  int tile = rem >> 7;
  int q = (rem >> 6) & 1;
  int lane = rem & 63;
  int c = tile * 16 + (lane & 15);
  int kbase = q * 32 + (lane >> 4) * 8;
  size_t obase = ((size_t)t) * 8;   // == ((layer*32 + tile*2 + q)*64 + lane)*8
#pragma unroll
  for (int j = 0; j < 8; ++j) {
    float wv = Wg[(size_t)layer * 64 * 256 + (size_t)(kbase + j) * 256 + c];
    unsigned short hb = f2bf(wv);
    whi[obase + j] = hb;
    wlo[obase + j] = f2bf(wv - bf2f(hb));
  }
}

// xh = h @ Wg via MFMA. Block = 16 nodes; wave w = head w (col-tiles 4w..4w+3).
// A (h rows) loaded straight from global, hi/lo bf16 split; B from pre-packed
// whi/wlo; 6 MFMA per tile (AhBh*2 + AhBl*2 + AlBh*2). als/ald folded in.
__global__ __launch_bounds__(256, 4) void k_xh(const float* __restrict__ h,
    const unsigned short* __restrict__ whi, const unsigned short* __restrict__ wlo,
    const float* __restrict__ asrc, const float* __restrict__ adst,
    unsigned short* __restrict__ xhb, float* __restrict__ als,
    float* __restrict__ ald, int N)
{
  int tid = threadIdx.x, lane = tid & 63, w = tid >> 6;
  int n0 = blockIdx.x * 16;
  int r = lane & 15, kb = lane >> 4;
  int row = n0 + r; if (row >= N) row = N - 1;

  union UB { bf16x8 v; unsigned short u[8]; };
  UB Ahi[2], Alo[2];
#pragma unroll
  for (int q = 0; q < 2; ++q) {
    const float* ap = h + (size_t)row * 64 + q * 32 + kb * 8;
    float4 f0 = *(const float4*)ap;
    float4 f1 = *(const float4*)(ap + 4);
    float xf[8] = {f0.x, f0.y, f0.z, f0.w, f1.x, f1.y, f1.z, f1.w};
#pragma unroll
    for (int j = 0; j < 8; ++j) {
      unsigned short hb = f2bf(xf[j]);
      Ahi[q].u[j] = hb;
      Alo[q].u[j] = f2bf(xf[j] - bf2f(hb));
    }
  }

  float alsp[4] = {0.f, 0.f, 0.f, 0.f};
  float aldp[4] = {0.f, 0.f, 0.f, 0.f};
#pragma unroll
  for (int tt = 0; tt < 4; ++tt) {
    int tile = w * 4 + tt;
    const unsigned short* bh = whi + ((size_t)(tile * 2) * 64 + lane) * 8;
    const unsigned short* bl = wlo + ((size_t)(tile * 2) * 64 + lane) * 8;
    UB Bh0, Bh1, Bl0, Bl1;
    *(uint4*)Bh0.u = *(const uint4*)bh;
    *(uint4*)Bh1.u = *(const uint4*)(bh + 512);  // q=1 -> +64*8
    *(uint4*)Bl0.u = *(const uint4*)bl;
    *(uint4*)Bl1.u = *(const uint4*)(bl + 512);
    f32x4 C = {0.f, 0.f, 0.f, 0.f};
    C = __builtin_amdgcn_mfma_f32_16x16x32_bf16(Ahi[0].v, Bh0.v, C, 0, 0, 0);
    C = __builtin_amdgcn_mfma_f32_16x16x32_bf16(Ahi[1].v, Bh1.v, C, 0, 0, 0);
    C = __builtin_amdgcn_mfma_f32_16x16x32_bf16(Ahi[0].v, Bl0.v, C, 0, 0, 0);
    C = __builtin_amdgcn_mfma_f32_16x16x32_bf16(Ahi[1].v, Bl1.v, C, 0, 0, 0);
    C = __builtin_amdgcn_mfma_f32_16x16x32_bf16(Alo[0].v, Bh0.v, C, 0, 0, 0);
    C = __builtin_amdgcn_mfma_f32_16x16x32_bf16(Alo[1].v, Bh1.v, C, 0, 0, 0);
    int col = tile * 16 + r;
    float a_s = asrc[col], a_d = adst[col];
#pragma unroll
    for (int reg = 0; reg < 4; ++reg) {
      int n = n0 + kb * 4 + reg;
      if (n < N) xhb[(size_t)n * 256 + col] = f2bf(C[reg]);
      alsp[reg] = fmaf(C[reg], a_s, alsp[reg]);
      aldp[reg] = fmaf(C[reg], a_d, aldp[reg]);
    }
  }
  // reduce over the 16 lanes of each kb-group (cols) -> per-row head logits
#pragma unroll
  for (int d = 1; d < 16; d <<= 1) {
#pragma unroll
    for (int reg = 0; reg < 4; ++reg) {
      alsp[reg] += __shfl_xor(alsp[reg], d, 64);
      aldp[reg] += __shfl_xor(aldp[reg], d, 64);
    }
  }
  if (r == 0) {
#pragma unroll
    for (int reg = 0; reg < 4; ++reg) {
      int n = n0 + kb * 4 + reg;
      if (n < N) { als[n * 4 + w] = alsp[reg]; ald[n * 4 + w] = aldp[reg]; }
    }
  }
}

// One wave per node. Edge-parallel softmax; gather loop unrolled x2 with
// paired loads (4 VMEM in flight) to hide L2/L3 latency.
__global__ __launch_bounds__(256) void k_agg(const unsigned short* __restrict__ xhb,
    const float* __restrict__ als, const float* __restrict__ ald,
    const int* __restrict__ rowstart, const int* __restrict__ srcs,
    const float* __restrict__ bias, const float* __restrict__ g,
    const float* __restrict__ b, float* __restrict__ h, int N, int doRes)
{
  __shared__ float4 pb[4][64];
  __shared__ int sb[4][64];
  int lane = threadIdx.x & 63;
  int wid = threadIdx.x >> 6;
  int n = blockIdx.x * 4 + wid;
  if (n >= N) return;
  int beg = rowstart[n], end = rowstart[n + 1];
  int deg = end - beg;
  const float4 adv = *(const float4*)(ald + (size_t)n * 4);
  const unsigned* xu = (const unsigned*)xhb;
  bool lo32 = (lane < 32);

  float l0 = 0.f, l1 = 0.f, l2 = 0.f, l3 = 0.f;
  float A0 = 0.f, B0 = 0.f, A1 = 0.f, B1 = 0.f;

  if (deg <= 64) {
    int e = beg + lane;
    int ce = (e < end) ? e : (end - 1);
    int s = srcs[ce];
    float4 av = *(const float4*)(als + (size_t)s * 4);
    float e0 = lrelu02(av.x + adv.x);
    float e1 = lrelu02(av.y + adv.y);
    float e2 = lrelu02(av.z + adv.z);
    float e3 = lrelu02(av.w + adv.w);
    bool act = (e < end);
    float m0 = wave_max(act ? e0 : -1e30f);
    float m1 = wave_max(act ? e1 : -1e30f);
    float m2 = wave_max(act ? e2 : -1e30f);
    float m3 = wave_max(act ? e3 : -1e30f);
    float p0 = act ? __expf(e0 - m0) : 0.f;
    float p1 = act ? __expf(e1 - m1) : 0.f;
    float p2 = act ? __expf(e2 - m2) : 0.f;
    float p3 = act ? __expf(e3 - m3) : 0.f;
    l0 = p0; l1 = p1; l2 = p2; l3 = p3;
    pb[wid][lane] = make_float4(p0, p1, p2, p3);
    sb[wid][lane] = s;
    int j = 0;
    for (; j + 1 < deg; j += 2) {
      float4 pa = pb[wid][j];
      float4 pc = pb[wid][j + 1];
      int sa = sb[wid][j];
      int sc = sb[wid][j + 1];
      const unsigned* ra = xu + (size_t)sa * 128;
      const unsigned* rc = xu + (size_t)sc * 128;
      unsigned ua0 = ra[lane], ua1 = ra[64 + lane];
      unsigned uc0 = rc[lane], uc1 = rc[64 + lane];
      float pA = lo32 ? pa.x : pa.y;
      float pB = lo32 ? pa.z : pa.w;
      float qA = lo32 ? pc.x : pc.y;
      float qB = lo32 ? pc.z : pc.w;
      A0 = fmaf(pA, __uint_as_float(ua0 << 16), A0);
      B0 = fmaf(pA, __uint_as_float(ua0 & 0xffff0000u), B0);
      A1 = fmaf(pB, __uint_as_float(ua1 << 16), A1);
      B1 = fmaf(pB, __uint_as_float(ua1 & 0xffff0000u), B1);
      A0 = fmaf(qA, __uint_as_float(uc0 << 16), A0);
      B0 = fmaf(qA, __uint_as_float(uc0 & 0xffff0000u), B0);
      A1 = fmaf(qB, __uint_as_float(uc1 << 16), A1);
      B1 = fmaf(qB, __uint_as_float(uc1 & 0xffff0000u), B1);
    }
    if (j < deg) {
      float4 p = pb[wid][j];
      int sj = sb[wid][j];
      const unsigned* row = xu + (size_t)sj * 128;
      unsigned u0 = row[lane];
      unsigned u1 = row[64 + lane];
      float pA = lo32 ? p.x : p.y;
      float pB = lo32 ? p.z : p.w;
      A0 = fmaf(pA, __uint_as_float(u0 << 16), A0);
      B0 = fmaf(pA, __uint_as_float(u0 & 0xffff0000u), B0);
      A1 = fmaf(pB, __uint_as_float(u1 << 16), A1);
      B1 = fmaf(pB, __uint_as_float(u1 & 0xffff0000u), B1);
    }
  } else {
    float m0 = -1e30f, m1 = -1e30f, m2 = -1e30f, m3 = -1e30f;
    for (int base = beg; base < end; base += 64) {
      int e = base + lane;
      int ce = (e < end) ? e : (end - 1);
      int s = srcs[ce];
      float4 av = *(const float4*)(als + (size_t)s * 4);
      bool act = (e < end);
      m0 = fmaxf(m0, act ? lrelu02(av.x + adv.x) : -1e30f);
      m1 = fmaxf(m1, act ? lrelu02(av.y + adv.y) : -1e30f);
      m2 = fmaxf(m2, act ? lrelu02(av.z + adv.z) : -1e30f);
      m3 = fmaxf(m3, act ? lrelu02(av.w + adv.w) : -1e30f);
    }
    m0 = wave_max(m0); m1 = wave_max(m1); m2 = wave_max(m2); m3 = wave_max(m3);
    for (int base = beg; base < end; base += 64) {
      int e = base + lane;
      int ce = (e < end) ? e : (end - 1);
      int s = srcs[ce];
      float4 av = *(const float4*)(als + (size_t)s * 4);
      bool act = (e < end);
      float p0 = act ? __expf(lrelu02(av.x + adv.x) - m0) : 0.f;
      float p1 = act ? __expf(lrelu02(av.y + adv.y) - m1) : 0.f;
      float p2 = act ? __expf(lrelu02(av.z + adv.z) - m2) : 0.f;
      float p3 = act ? __expf(lrelu02(av.w + adv.w) - m3) : 0.f;
      l0 += p0; l1 += p1; l2 += p2; l3 += p3;
      pb[wid][lane] = make_float4(p0, p1, p2, p3);
      sb[wid][lane] = s;
      int cnt = end - base; if (cnt > 64) cnt = 64;
      for (int j = 0; j < cnt; ++j) {
        float4 p = pb[wid][j];
        int sj = sb[wid][j];
        const unsigned* row = xu + (size_t)sj * 128;
        unsigned u0 = row[lane];
        unsigned u1 = row[64 + lane];
        float pA = lo32 ? p.x : p.y;
        float pB = lo32 ? p.z : p.w;
        A0 = fmaf(pA, __uint_as_float(u0 << 16), A0);
        B0 = fmaf(pA, __uint_as_float(u0 & 0xffff0000u), B0);
        A1 = fmaf(pB, __uint_as_float(u1 << 16), A1);
        B1 = fmaf(pB, __uint_as_float(u1 & 0xffff0000u), B1);
      }
    }
  }

  l0 = wave_sum(l0); l1 = wave_sum(l1); l2 = wave_sum(l2); l3 = wave_sum(l3);
  float i0 = 1.f / (l0 + 1e-16f), i1 = 1.f / (l1 + 1e-16f);
  float i2 = 1.f / (l2 + 1e-16f), i3 = 1.f / (l3 + 1e-16f);
  float iA = lo32 ? i0 : i1;
  float iB = lo32 ? i2 : i3;
  float tA = A0 * iA + A1 * iB;
  float tB = B0 * iA + B1 * iB;
  float sA = tA + __shfl_xor(tA, 32, 64);
  float sB = tB + __shfl_xor(tB, 32, 64);
  int cA = 2 * (lane & 31);
  float2 bv = *(const float2*)(bias + cA);
  float oA = 0.25f * sA + bv.x;
  float oB = 0.25f * sB + bv.y;
  float mu = wave_sum(oA + oB) * (1.f / 128.f);
  float dA = oA - mu, dB = oB - mu;
  float var = wave_sum(dA * dA + dB * dB) * (1.f / 128.f);
  float rinv = rsqrtf(var + 1e-5f);
  float2 gv = *(const float2*)(g + cA);
  float2 bbv = *(const float2*)(b + cA);
  float rA = fmaxf(dA * rinv * gv.x + bbv.x, 0.f);
  float rB = fmaxf(dB * rinv * gv.y + bbv.y, 0.f);
  float* hp = h + (size_t)n * 64 + cA;
  if (doRes) { float2 hv = *(const float2*)hp; rA += hv.x; rB += hv.y; }
  if (lo32) { float2 o2; o2.x = rA; o2.y = rB; *(float2*)hp = o2; }
}

// Fused global_mean_pool + output GEMM (batch sorted -> contiguous ranges).
__global__ __launch_bounds__(256) void k_graph(const float* __restrict__ h,
    const int* __restrict__ batch, const float* __restrict__ Wout,
    const float* __restrict__ bout, float* __restrict__ out, int N)
{
  __shared__ float sm[4][64];
  int g = blockIdx.x;
  int tid = threadIdx.x, lane = tid & 63, wid = tid >> 6;
  int lo = 0, hi = N;
  while (lo < hi) { int mid = (lo + hi) >> 1; if (batch[mid] < g) lo = mid + 1; else hi = mid; }
  int start = lo;
  hi = N;
  while (lo < hi) { int mid = (lo + hi) >> 1; if (batch[mid] < g + 1) lo = mid + 1; else hi = mid; }
  int end = lo;
  float acc = 0.f;
  for (int n = start + wid; n < end; n += 4) acc += h[(size_t)n * 64 + lane];
  sm[wid][lane] = acc;
  __syncthreads();
  if (wid == 0) {
    float s = sm[0][lane] + sm[1][lane] + sm[2][lane] + sm[3][lane];
    float cf = (float)(end - start);
    sm[0][lane] = s / fmaxf(cf, 1.f);
  }
  __syncthreads();
  if (tid < 32) {
    float s = 0.f;
#pragma unroll
    for (int c = 0; c < 64; ++c) s = fmaf(sm[0][c], Wout[c * 32 + tid], s);
    out[g * 32 + tid] = s + bout[tid];
  }
}

extern "C" void kernel_launch(void* const* d_in, const int* in_sizes, int n_in,
                              void* d_out, int out_size, void* d_ws, size_t ws_size,
                              hipStream_t stream) {
  const float* x    = (const float*)d_in[0];
  const int*   ei   = (const int*)d_in[1];
  const int*   batch= (const int*)d_in[2];
  const float* Win  = (const float*)d_in[3];
  const float* bin  = (const float*)d_in[4];
  const float* Wgat = (const float*)d_in[5];
  const float* asrc = (const float*)d_in[6];
  const float* adst = (const float*)d_in[7];
  const float* bgat = (const float*)d_in[8];
  const float* lng  = (const float*)d_in[9];
  const float* lnb  = (const float*)d_in[10];
  const float* Wout = (const float*)d_in[11];
  const float* bout = (const float*)d_in[12];
  float* out = (float*)d_out;

  int N  = in_sizes[0] / 32;
  int E  = in_sizes[1] / 2;
  int NG = out_size / 32;
  int L  = in_sizes[5] / (64 * 256);

  char* w = (char*)d_ws;
  unsigned short* whi = (unsigned short*)w; w += (size_t)L * 16384 * 2;
  unsigned short* wlo = (unsigned short*)w; w += (size_t)L * 16384 * 2;
  unsigned short* xhb = (unsigned short*)w; w += (size_t)N * 256 * 2;
  float* h  = (float*)w;       w += (size_t)N * 64 * 4;
  float* als= (float*)w;       w += (size_t)N * 4 * 4;
  float* ald= (float*)w;       w += (size_t)N * 4 * 4;
  int* rowstart = (int*)w;     w += (size_t)(N + 1) * 4;
  int* counter  = (int*)w;     w += (size_t)N * 4;
  int* srcs     = (int*)w;     w += (size_t)(E + N) * 4;

  const int* esrc = ei;       // edge_index[0]
  const int* edst = ei + E;   // edge_index[1]

  // W pre-pack (B-fragment order, hi/lo) + input layer
  k_wprep<<<(L * 2048 + 255) / 256, 256, 0, stream>>>(Wgat, whi, wlo, L);
  k_input<<<(N + 63) / 64, 256, 0, stream>>>(x, Win, bin, h, N);

  // CSR build (dst-grouped), self-loops included via deg init = 1
  k_set1<<<(N + 255) / 256, 256, 0, stream>>>(counter, N);
  k_count<<<(E + 255) / 256, 256, 0, stream>>>(edst, counter, E);
  k_scan<<<1, 1024, 0, stream>>>(counter, rowstart, N);
  k_fill<<<(E + N + 255) / 256, 256, 0, stream>>>(esrc, edst, counter, srcs, E, N);

  for (int i = 0; i < L; ++i) {
    k_xh<<<(N + 15) / 16, 256, 0, stream>>>(h, whi + (size_t)i * 16384,
        wlo + (size_t)i * 16384, asrc + i * 256, adst + i * 256, xhb, als, ald, N);
    k_agg<<<(N + 3) / 4, 256, 0, stream>>>(xhb, als, ald, rowstart, srcs,
        bgat + i * 64, lng + i * 64, lnb + i * 64, h, N, i > 0 ? 1 : 0);
  }

  // fused mean pool + output GEMM (no atomics; batch is sorted)
  k_graph<<<NG, 256, 0, stream>>>(h, batch, Wout, bout, out, N);
}